// Round 1
// baseline (318.383 us; speedup 1.0000x reference)
//
#include <hip/hip_runtime.h>
#include <stdint.h>

typedef float  v4f  __attribute__((ext_vector_type(4)));
typedef int    v4i  __attribute__((ext_vector_type(4)));
typedef __bf16 v8bf __attribute__((ext_vector_type(8)));
typedef __bf16 v4bf __attribute__((ext_vector_type(4)));

#define BATCH  2
#define NQ     4096
#define MK     1024
#define DMODEL 512
#define DCTX   768
#define NH     8
#define DH     64

// scal[0]=amax_q bits, [1]=amax_k, [2]=amax_v, [3]=max(1/Z) bits
__global__ void k_init(unsigned* scal) {
  if (threadIdx.x < 4) scal[threadIdx.x] = 0u;
}

// W[K][512] fp32 -> Wt[512][K] bf16 (so GEMM B-operand stages contiguous along K)
__global__ __launch_bounds__(256) void k_wtrans(
    const float* __restrict__ Wq, const float* __restrict__ Wk,
    const float* __restrict__ Wv, const float* __restrict__ Wo,
    __bf16* __restrict__ Wq_t, __bf16* __restrict__ Wk_t,
    __bf16* __restrict__ Wv_t, __bf16* __restrict__ Wo_t) {
  const float* src; __bf16* dst; int K;
  switch (blockIdx.z) {
    case 0:  src = Wq; dst = Wq_t; K = DMODEL; break;
    case 1:  src = Wk; dst = Wk_t; K = DCTX;   break;
    case 2:  src = Wv; dst = Wv_t; K = DCTX;   break;
    default: src = Wo; dst = Wo_t; K = DMODEL; break;
  }
  int k0 = blockIdx.y * 32;
  if (k0 >= K) return;
  int n0 = blockIdx.x * 32;
  __shared__ __bf16 tile[32][33];
  int c = threadIdx.x & 31, r0 = threadIdx.x >> 5;
  for (int i = 0; i < 4; ++i) {
    int r = r0 + i * 8;
    tile[c][r] = (__bf16)src[(size_t)(k0 + r) * DMODEL + n0 + c];
  }
  __syncthreads();
  for (int i = 0; i < 4; ++i) {
    int r = r0 + i * 8;
    dst[(size_t)(n0 + r) * K + k0 + c] = tile[r][c];
  }
}

// C[M][N] = A[M][K](f32) @ Bt[N][K](bf16)^T, 128x128 tile, BK=32, 4 waves x 64x64
template<bool BIAS, bool AMAX>
__global__ __launch_bounds__(256, 2) void k_gemm(
    const float* __restrict__ A, const __bf16* __restrict__ Bt,
    float* __restrict__ C, int M, int N, int K,
    const float* __restrict__ bias, unsigned* __restrict__ amax) {
  __shared__ __bf16 As[128 * 40];  // stride 40 (pad) -> conflict-free b128 frag reads
  __shared__ __bf16 Bs[128 * 40];
  const int tid = threadIdx.x;
  const int lane = tid & 63, wave = tid >> 6;
  const int l15 = lane & 15, g = lane >> 4;
  const int row0 = blockIdx.x * 128, col0 = blockIdx.y * 128;
  const int wrow = (wave >> 1) * 64, wcol = (wave & 1) * 64;

  v4f acc[4][4] = {};

  for (int k0 = 0; k0 < K; k0 += 32) {
#pragma unroll
    for (int i = 0; i < 4; ++i) {   // A: 128x32 f32 -> bf16
      int f = tid + 256 * i;
      int r = f >> 3, c4 = (f & 7) << 2;
      float4 av = *(const float4*)(A + (size_t)(row0 + r) * K + k0 + c4);
      v4bf ap = { (__bf16)av.x, (__bf16)av.y, (__bf16)av.z, (__bf16)av.w };
      *(v4bf*)(&As[r * 40 + c4]) = ap;
    }
#pragma unroll
    for (int i = 0; i < 2; ++i) {   // B: 128x32 bf16
      int f = tid + 256 * i;
      int r = f >> 2, c8 = (f & 3) << 3;
      *(v8bf*)(&Bs[r * 40 + c8]) =
          *(const v8bf*)(Bt + (size_t)(col0 + r) * K + k0 + c8);
    }
    __syncthreads();
    v8bf af[4], bfr[4];
#pragma unroll
    for (int i = 0; i < 4; ++i)
      af[i] = *(const v8bf*)(&As[(wrow + i * 16 + l15) * 40 + g * 8]);
#pragma unroll
    for (int j = 0; j < 4; ++j)
      bfr[j] = *(const v8bf*)(&Bs[(wcol + j * 16 + l15) * 40 + g * 8]);
#pragma unroll
    for (int i = 0; i < 4; ++i)
#pragma unroll
      for (int j = 0; j < 4; ++j)
        acc[i][j] = __builtin_amdgcn_mfma_f32_16x16x32_bf16(af[i], bfr[j], acc[i][j], 0, 0, 0);
    __syncthreads();
  }

  float lmax = 0.0f;
#pragma unroll
  for (int j = 0; j < 4; ++j) {
    int col = col0 + wcol + j * 16 + l15;
    float bv = BIAS ? bias[col] : 0.0f;
#pragma unroll
    for (int i = 0; i < 4; ++i) {
#pragma unroll
      for (int r = 0; r < 4; ++r) {
        int row = row0 + wrow + i * 16 + g * 4 + r;  // C/D: col=lane&15, row=quad*4+reg
        float cv = acc[i][j][r] + bv;
        C[(size_t)row * N + col] = cv;
        if (AMAX) lmax = fmaxf(lmax, fabsf(cv));
      }
    }
  }
  if (AMAX) {
    for (int off = 32; off > 0; off >>= 1)
      lmax = fmaxf(lmax, __shfl_xor(lmax, off, 64));
    if (lane == 0) atomicMax(amax, __float_as_uint(lmax));  // nonneg float bits monotone
  }
}

__global__ __launch_bounds__(256) void k_quant_qk(
    const float* __restrict__ qf, const float* __restrict__ kf,
    int8_t* __restrict__ q8, int8_t* __restrict__ k8,
    const unsigned* __restrict__ scal) {
  const int Q4 = BATCH * NQ * DMODEL / 4;
  const int K4 = BATCH * MK * DMODEL / 4;
  int idx = blockIdx.x * 256 + threadIdx.x;
  float4 v; int8_t* dst; float s;
  if (idx < Q4) {
    v = ((const float4*)qf)[idx];
    dst = q8 + (size_t)idx * 4;
    s = 127.0f / __uint_as_float(scal[0]);
  } else {
    int j = idx - Q4;
    if (j >= K4) return;
    v = ((const float4*)kf)[j];
    dst = k8 + (size_t)j * 4;
    s = 127.0f / __uint_as_float(scal[1]);
  }
  int a0 = __float2int_rn(v.x * s), a1 = __float2int_rn(v.y * s);
  int a2 = __float2int_rn(v.z * s), a3 = __float2int_rn(v.w * s);
  a0 = max(-128, min(127, a0)); a1 = max(-128, min(127, a1));
  a2 = max(-128, min(127, a2)); a3 = max(-128, min(127, a3));
  unsigned p = (unsigned)(a0 & 255) | ((unsigned)(a1 & 255) << 8) |
               ((unsigned)(a2 & 255) << 16) | ((unsigned)(a3 & 255) << 24);
  *(unsigned*)dst = p;
}

// v[b][m][h*64+dh] f32 -> v8t[bh][dh][m] int8 (PV B-frags contiguous along m)
__global__ __launch_bounds__(256) void k_vtrans(
    const float* __restrict__ vf, int8_t* __restrict__ v8t,
    const unsigned* __restrict__ scal) {
  const float s = 127.0f / __uint_as_float(scal[2]);
  int bh = blockIdx.y;
  int b = bh >> 3, h = bh & 7;
  int j0 = blockIdx.x * 64;
  __shared__ int8_t tile[64][80];
  int t = threadIdx.x;
  int j = t >> 2, dh0 = (t & 3) << 4;
  const float* src = vf + (size_t)(b * MK + j0 + j) * DMODEL + h * DH + dh0;
#pragma unroll
  for (int i = 0; i < 16; i += 4) {
    float4 v = *(const float4*)(src + i);
    int a0 = __float2int_rn(v.x * s), a1 = __float2int_rn(v.y * s);
    int a2 = __float2int_rn(v.z * s), a3 = __float2int_rn(v.w * s);
    tile[dh0 + i + 0][j] = (int8_t)max(-128, min(127, a0));
    tile[dh0 + i + 1][j] = (int8_t)max(-128, min(127, a1));
    tile[dh0 + i + 2][j] = (int8_t)max(-128, min(127, a2));
    tile[dh0 + i + 3][j] = (int8_t)max(-128, min(127, a3));
  }
  __syncthreads();
  int dh = t >> 2, jb = (t & 3) << 4;
  v4i val = *(const v4i*)(&tile[dh][jb]);
  *(v4i*)(v8t + (size_t)(bh * DH + dh) * MK + j0 + jb) = val;
}

// pass 1: S^T tiles (A=k, B=q) so each lane owns one q-row; online (m, Z); atomicMax(1/Z)
__global__ __launch_bounds__(256) void k_pass1(
    const int8_t* __restrict__ q8, const int8_t* __restrict__ k8,
    float2* __restrict__ mz, unsigned* __restrict__ scal) {
  int bh = blockIdx.y, b = bh >> 3, h = bh & 7;
  int wave = threadIdx.x >> 6, lane = threadIdx.x & 63;
  int l15 = lane & 15, g = lane >> 4;
  int row0 = blockIdx.x * 64 + wave * 16;
  const float aq = __uint_as_float(scal[0]), ak = __uint_as_float(scal[1]);
  const float alpha = (aq * ak) * (0.125f / (127.0f * 127.0f));
  const v4i z4 = {0, 0, 0, 0};
  v4i qfrag = *(const v4i*)(q8 + (size_t)(b * NQ + row0 + l15) * DMODEL + h * DH + g * 16);
  const int8_t* kbase = k8 + (size_t)b * MK * DMODEL + h * DH + g * 16;
  float m = -INFINITY, z = 0.0f;
  for (int kt = 0; kt < MK / 16; ++kt) {
    v4i kfrag = *(const v4i*)(kbase + (size_t)(kt * 16 + l15) * DMODEL);
    v4i sa = __builtin_amdgcn_mfma_i32_16x16x64_i8(kfrag, qfrag, z4, 0, 0, 0);
    float s0 = (float)sa[0] * alpha, s1 = (float)sa[1] * alpha;
    float s2 = (float)sa[2] * alpha, s3 = (float)sa[3] * alpha;
    float nm = fmaxf(fmaxf(fmaxf(s0, s1), fmaxf(s2, s3)), m);
    z = z * __expf(m - nm) +
        __expf(s0 - nm) + __expf(s1 - nm) + __expf(s2 - nm) + __expf(s3 - nm);
    m = nm;
  }
  // combine the 4 lane-copies of each q-row (xor 16, 32)
  for (int off = 16; off <= 32; off <<= 1) {
    float om = __shfl_xor(m, off, 64), oz = __shfl_xor(z, off, 64);
    float nm = fmaxf(m, om);
    z = z * __expf(m - nm) + oz * __expf(om - nm);
    m = nm;
  }
  float invz = 1.0f / z;  // = row max of softmax
  if (lane < 16) mz[(size_t)bh * NQ + row0 + l15] = make_float2(m, invz);
  float mx = invz;
  for (int off = 1; off < 16; off <<= 1) mx = fmaxf(mx, __shfl_xor(mx, off, 64));
  if (lane == 0) atomicMax(scal + 3, __float_as_uint(mx));
}

// pass 2: recompute S, quantize attn in-register, LDS C->A transpose, int8 PV
__global__ __launch_bounds__(256) void k_pass2(
    const int8_t* __restrict__ q8, const int8_t* __restrict__ k8,
    const int8_t* __restrict__ v8t, const float2* __restrict__ mz,
    const unsigned* __restrict__ scal, float* __restrict__ o) {
  __shared__ int8_t attn_lds[4][16 * 80];  // per-wave 16 rows x 64 keys, stride 80
  int bh = blockIdx.y, b = bh >> 3, h = bh & 7;
  int wave = threadIdx.x >> 6, lane = threadIdx.x & 63;
  int l15 = lane & 15, g = lane >> 4;
  int row0 = blockIdx.x * 64 + wave * 16;
  const float aq = __uint_as_float(scal[0]), ak = __uint_as_float(scal[1]);
  const float avv = __uint_as_float(scal[2]), izm = __uint_as_float(scal[3]);
  const float alpha = (aq * ak) * (0.125f / (127.0f * 127.0f));
  const float inv_da = 127.0f / izm;               // 1/delta_attn
  const float oscale = (izm / 127.0f) * (avv / 127.0f);  // delta_attn * delta_v
  const v4i z4 = {0, 0, 0, 0};
  v4i qfrag = *(const v4i*)(q8 + (size_t)(b * NQ + row0 + l15) * DMODEL + h * DH + g * 16);
  float2 mzv = mz[(size_t)bh * NQ + row0 + l15];
  const float mrow = mzv.x;
  const float crow = mzv.y * inv_da;  // invZ / delta_attn
  const int8_t* kbase = k8 + (size_t)b * MK * DMODEL + h * DH + g * 16;
  const int8_t* vbase = v8t + (size_t)bh * DH * MK;
  int8_t* alds = attn_lds[wave];
  v4i pacc[4] = {};

  for (int kt = 0; kt < MK / 64; ++kt) {
#pragma unroll
    for (int t = 0; t < 4; ++t) {
      int key0 = kt * 64 + t * 16;
      v4i kfrag = *(const v4i*)(kbase + (size_t)(key0 + l15) * DMODEL);
      v4i sa = __builtin_amdgcn_mfma_i32_16x16x64_i8(kfrag, qfrag, z4, 0, 0, 0);
      unsigned packed = 0;
#pragma unroll
      for (int r = 0; r < 4; ++r) {
        float s = (float)sa[r] * alpha;
        float a = __expf(s - mrow) * crow;
        int ai = __float2int_rn(a);
        ai = ai < 0 ? 0 : (ai > 127 ? 127 : ai);
        packed |= ((unsigned)ai) << (8 * r);
      }
      // C-layout: col(l15)=q-row, row(g*4+r)=key -> store at [qrow][key_local]
      *(unsigned*)(alds + l15 * 80 + t * 16 + g * 4) = packed;
    }
    __syncthreads();
    v4i afrag = *(const v4i*)(alds + l15 * 80 + g * 16);  // A-layout read
#pragma unroll
    for (int t = 0; t < 4; ++t) {
      v4i bfrag = *(const v4i*)(vbase + (size_t)(t * 16 + l15) * MK + kt * 64 + g * 16);
      pacc[t] = __builtin_amdgcn_mfma_i32_16x16x64_i8(afrag, bfrag, pacc[t], 0, 0, 0);
    }
    __syncthreads();
  }
#pragma unroll
  for (int t = 0; t < 4; ++t)
#pragma unroll
    for (int r = 0; r < 4; ++r) {
      int row = row0 + g * 4 + r;
      o[(size_t)(b * NQ + row) * DMODEL + h * DH + t * 16 + l15] =
          (float)pacc[t][r] * oscale;
    }
}

extern "C" void kernel_launch(void* const* d_in, const int* in_sizes, int n_in,
                              void* d_out, int out_size, void* d_ws, size_t ws_size,
                              hipStream_t stream) {
  (void)in_sizes; (void)n_in; (void)out_size; (void)ws_size;
  const float* x   = (const float*)d_in[0];
  const float* ctx = (const float*)d_in[1];
  const float* Wq  = (const float*)d_in[2];
  const float* Wk  = (const float*)d_in[3];
  const float* Wv  = (const float*)d_in[4];
  const float* Wo  = (const float*)d_in[5];
  const float* bo  = (const float*)d_in[6];
  float* out = (float*)d_out;

  char* ws = (char*)d_ws;
  size_t off = 0;
  auto alloc = [&](size_t bytes) {
    char* p = ws + off;
    off += (bytes + 255) & ~(size_t)255;
    return p;
  };
  unsigned* scal = (unsigned*)alloc(16);
  __bf16* Wq_t = (__bf16*)alloc((size_t)512 * 512 * 2);
  __bf16* Wk_t = (__bf16*)alloc((size_t)512 * 768 * 2);
  __bf16* Wv_t = (__bf16*)alloc((size_t)512 * 768 * 2);
  __bf16* Wo_t = (__bf16*)alloc((size_t)512 * 512 * 2);
  float* qf = (float*)alloc((size_t)BATCH * NQ * DMODEL * 4);  // later reused as o
  float* kf = (float*)alloc((size_t)BATCH * MK * DMODEL * 4);
  float* vf = (float*)alloc((size_t)BATCH * MK * DMODEL * 4);
  int8_t* q8 = (int8_t*)alloc((size_t)BATCH * NQ * DMODEL);
  int8_t* k8 = (int8_t*)alloc((size_t)BATCH * MK * DMODEL);
  int8_t* v8t = (int8_t*)alloc((size_t)BATCH * NH * DH * MK);
  float2* mz = (float2*)alloc((size_t)BATCH * NH * NQ * 8);
  float* o = qf;  // q_f32 dead after quantization; alias saves 16.8 MB

  k_init<<<1, 64, 0, stream>>>(scal);
  k_wtrans<<<dim3(16, 24, 4), 256, 0, stream>>>(Wq, Wk, Wv, Wo, Wq_t, Wk_t, Wv_t, Wo_t);
  k_gemm<false, true><<<dim3(64, 4), 256, 0, stream>>>(x,   Wq_t, qf, 8192, 512, 512, nullptr, scal + 0);
  k_gemm<false, true><<<dim3(16, 4), 256, 0, stream>>>(ctx, Wk_t, kf, 2048, 512, 768, nullptr, scal + 1);
  k_gemm<false, true><<<dim3(16, 4), 256, 0, stream>>>(ctx, Wv_t, vf, 2048, 512, 768, nullptr, scal + 2);
  k_quant_qk<<<5120, 256, 0, stream>>>(qf, kf, q8, k8, scal);
  k_vtrans<<<dim3(16, 16), 256, 0, stream>>>(vf, v8t, scal);
  k_pass1<<<dim3(64, 16), 256, 0, stream>>>(q8, k8, mz, scal);
  k_pass2<<<dim3(64, 16), 256, 0, stream>>>(q8, k8, v8t, mz, scal, o);
  k_gemm<true, false><<<dim3(64, 4), 256, 0, stream>>>(o, Wo_t, out, 8192, 512, 512, bo, nullptr);
}

// Round 2
// 250.071 us; speedup vs baseline: 1.2732x; 1.2732x over previous
//
#include <hip/hip_runtime.h>
#include <stdint.h>

typedef float  v4f  __attribute__((ext_vector_type(4)));
typedef int    v4i  __attribute__((ext_vector_type(4)));
typedef __bf16 v8bf __attribute__((ext_vector_type(8)));
typedef __bf16 v4bf __attribute__((ext_vector_type(4)));

#define BATCH  2
#define NQ     4096
#define MK     1024
#define DMODEL 512
#define DCTX   768
#define NH     8
#define DH     64

// scal[0]=amax_q bits, [1]=amax_k, [2]=amax_v, [3]=max(1/Z) bits (all nonneg floats)
__global__ void k_init(unsigned* scal) {
  if (threadIdx.x < 4) scal[threadIdx.x] = 0u;
}

// W[K][512] fp32 -> Wt[512][K] bf16 (so GEMM B-operand stages contiguous along K)
__global__ __launch_bounds__(256) void k_wtrans(
    const float* __restrict__ Wq, const float* __restrict__ Wk,
    const float* __restrict__ Wv, const float* __restrict__ Wo,
    __bf16* __restrict__ Wq_t, __bf16* __restrict__ Wk_t,
    __bf16* __restrict__ Wv_t, __bf16* __restrict__ Wo_t) {
  const float* src; __bf16* dst; int K;
  switch (blockIdx.z) {
    case 0:  src = Wq; dst = Wq_t; K = DMODEL; break;
    case 1:  src = Wk; dst = Wk_t; K = DCTX;   break;
    case 2:  src = Wv; dst = Wv_t; K = DCTX;   break;
    default: src = Wo; dst = Wo_t; K = DMODEL; break;
  }
  int k0 = blockIdx.y * 32;
  if (k0 >= K) return;
  int n0 = blockIdx.x * 32;
  __shared__ __bf16 tile[32][33];
  int c = threadIdx.x & 31, r0 = threadIdx.x >> 5;
  for (int i = 0; i < 4; ++i) {
    int r = r0 + i * 8;
    tile[c][r] = (__bf16)src[(size_t)(k0 + r) * DMODEL + n0 + c];
  }
  __syncthreads();
  for (int i = 0; i < 4; ++i) {
    int r = r0 + i * 8;
    dst[(size_t)(n0 + r) * K + k0 + c] = tile[r][c];
  }
}

// C[M][N] = A[M][K](f32) @ Bt[N][K](bf16)^T, 128x128 tile, BK=32, 4 waves x 64x64
template<bool BIAS, bool AMAX>
__global__ __launch_bounds__(256, 2) void k_gemm(
    const float* __restrict__ A, const __bf16* __restrict__ Bt,
    float* __restrict__ C, int M, int N, int K,
    const float* __restrict__ bias, unsigned* __restrict__ amax) {
  __shared__ __bf16 As[128 * 40];  // stride 40 (pad) -> conflict-free b128 frag reads
  __shared__ __bf16 Bs[128 * 40];
  __shared__ float redmax[4];
  const int tid = threadIdx.x;
  const int lane = tid & 63, wave = tid >> 6;
  const int l15 = lane & 15, g = lane >> 4;
  const int row0 = blockIdx.x * 128, col0 = blockIdx.y * 128;
  const int wrow = (wave >> 1) * 64, wcol = (wave & 1) * 64;

  v4f acc[4][4] = {};

  for (int k0 = 0; k0 < K; k0 += 32) {
#pragma unroll
    for (int i = 0; i < 4; ++i) {   // A: 128x32 f32 -> bf16
      int f = tid + 256 * i;
      int r = f >> 3, c4 = (f & 7) << 2;
      float4 av = *(const float4*)(A + (size_t)(row0 + r) * K + k0 + c4);
      v4bf ap = { (__bf16)av.x, (__bf16)av.y, (__bf16)av.z, (__bf16)av.w };
      *(v4bf*)(&As[r * 40 + c4]) = ap;
    }
#pragma unroll
    for (int i = 0; i < 2; ++i) {   // B: 128x32 bf16
      int f = tid + 256 * i;
      int r = f >> 2, c8 = (f & 3) << 3;
      *(v8bf*)(&Bs[r * 40 + c8]) =
          *(const v8bf*)(Bt + (size_t)(col0 + r) * K + k0 + c8);
    }
    __syncthreads();
    v8bf af[4], bfr[4];
#pragma unroll
    for (int i = 0; i < 4; ++i)
      af[i] = *(const v8bf*)(&As[(wrow + i * 16 + l15) * 40 + g * 8]);
#pragma unroll
    for (int j = 0; j < 4; ++j)
      bfr[j] = *(const v8bf*)(&Bs[(wcol + j * 16 + l15) * 40 + g * 8]);
#pragma unroll
    for (int i = 0; i < 4; ++i)
#pragma unroll
      for (int j = 0; j < 4; ++j)
        acc[i][j] = __builtin_amdgcn_mfma_f32_16x16x32_bf16(af[i], bfr[j], acc[i][j], 0, 0, 0);
    __syncthreads();
  }

  float lmax = 0.0f;
#pragma unroll
  for (int j = 0; j < 4; ++j) {
    int col = col0 + wcol + j * 16 + l15;
    float bv = BIAS ? bias[col] : 0.0f;
#pragma unroll
    for (int i = 0; i < 4; ++i) {
#pragma unroll
      for (int r = 0; r < 4; ++r) {
        int row = row0 + wrow + i * 16 + g * 4 + r;  // C/D: col=lane&15, row=quad*4+reg
        float cv = acc[i][j][r] + bv;
        C[(size_t)row * N + col] = cv;
        if (AMAX) lmax = fmaxf(lmax, fabsf(cv));
      }
    }
  }
  if (AMAX) {
    for (int off = 32; off > 0; off >>= 1)
      lmax = fmaxf(lmax, __shfl_xor(lmax, off, 64));
    if (lane == 0) redmax[wave] = lmax;
    __syncthreads();
    if (tid == 0) {
      float bm = fmaxf(fmaxf(redmax[0], redmax[1]), fmaxf(redmax[2], redmax[3]));
      atomicMax(amax, __float_as_uint(bm));  // nonneg float bits monotone
    }
  }
}

__global__ __launch_bounds__(256) void k_quant_qk(
    const float* __restrict__ qf, const float* __restrict__ kf,
    int8_t* __restrict__ q8, int8_t* __restrict__ k8,
    const unsigned* __restrict__ scal) {
  const int Q4 = BATCH * NQ * DMODEL / 4;
  const int K4 = BATCH * MK * DMODEL / 4;
  int idx = blockIdx.x * 256 + threadIdx.x;
  float4 v; int8_t* dst; float s;
  if (idx < Q4) {
    v = ((const float4*)qf)[idx];
    dst = q8 + (size_t)idx * 4;
    s = 127.0f / __uint_as_float(scal[0]);
  } else {
    int j = idx - Q4;
    if (j >= K4) return;
    v = ((const float4*)kf)[j];
    dst = k8 + (size_t)j * 4;
    s = 127.0f / __uint_as_float(scal[1]);
  }
  int a0 = __float2int_rn(v.x * s), a1 = __float2int_rn(v.y * s);
  int a2 = __float2int_rn(v.z * s), a3 = __float2int_rn(v.w * s);
  a0 = max(-128, min(127, a0)); a1 = max(-128, min(127, a1));
  a2 = max(-128, min(127, a2)); a3 = max(-128, min(127, a3));
  unsigned p = (unsigned)(a0 & 255) | ((unsigned)(a1 & 255) << 8) |
               ((unsigned)(a2 & 255) << 16) | ((unsigned)(a3 & 255) << 24);
  *(unsigned*)dst = p;
}

// v[b][m][h*64+dh] f32 -> v8t[bh][dh][m] int8 (PV B-frags contiguous along m)
__global__ __launch_bounds__(256) void k_vtrans(
    const float* __restrict__ vf, int8_t* __restrict__ v8t,
    const unsigned* __restrict__ scal) {
  const float s = 127.0f / __uint_as_float(scal[2]);
  int bh = blockIdx.y;
  int b = bh >> 3, h = bh & 7;
  int j0 = blockIdx.x * 64;
  __shared__ int8_t tile[64][80];
  int t = threadIdx.x;
  int j = t >> 2, dh0 = (t & 3) << 4;
  const float* src = vf + (size_t)(b * MK + j0 + j) * DMODEL + h * DH + dh0;
#pragma unroll
  for (int i = 0; i < 16; i += 4) {
    float4 v = *(const float4*)(src + i);
    int a0 = __float2int_rn(v.x * s), a1 = __float2int_rn(v.y * s);
    int a2 = __float2int_rn(v.z * s), a3 = __float2int_rn(v.w * s);
    tile[dh0 + i + 0][j] = (int8_t)max(-128, min(127, a0));
    tile[dh0 + i + 1][j] = (int8_t)max(-128, min(127, a1));
    tile[dh0 + i + 2][j] = (int8_t)max(-128, min(127, a2));
    tile[dh0 + i + 3][j] = (int8_t)max(-128, min(127, a3));
  }
  __syncthreads();
  int dh = t >> 2, jb = (t & 3) << 4;
  v4i val = *(const v4i*)(&tile[dh][jb]);
  *(v4i*)(v8t + (size_t)(bh * DH + dh) * MK + j0 + jb) = val;
}

// pass 1 v2: wave w handles keys [w*256,(w+1)*256) for all 64 q-rows.
// No-max z accumulation (scores tiny; exp2 can't overflow): z = sum exp2(s*a2).
// Row max tracked as integer max (only feeds the global attn scale).
__global__ __launch_bounds__(256) void k_pass1(
    const int8_t* __restrict__ q8, const int8_t* __restrict__ k8,
    float* __restrict__ invz, unsigned* __restrict__ scal) {
  __shared__ float zbuf[4][64];
  __shared__ int   mbuf[4][64];
  int bh = blockIdx.y, b = bh >> 3, h = bh & 7;
  int wave = threadIdx.x >> 6, lane = threadIdx.x & 63;
  int l15 = lane & 15, g = lane >> 4;
  int row0 = blockIdx.x * 64;
  const float aq = __uint_as_float(scal[0]), ak = __uint_as_float(scal[1]);
  const float alpha2 = (aq * ak) * (0.125f / (127.0f * 127.0f)) * 1.44269504f;
  const v4i z4 = {0, 0, 0, 0};
  v4i qfrag[4];
#pragma unroll
  for (int rg = 0; rg < 4; ++rg)
    qfrag[rg] = *(const v4i*)(q8 + (size_t)(b * NQ + row0 + rg * 16 + l15) * DMODEL + h * DH + g * 16);
  const int8_t* kbase = k8 + (size_t)b * MK * DMODEL + h * DH + g * 16 +
                        (size_t)wave * 256 * DMODEL;
  float z[4] = {0.f, 0.f, 0.f, 0.f};
  int mi[4] = {-(1 << 30), -(1 << 30), -(1 << 30), -(1 << 30)};
  for (int kt = 0; kt < 16; ++kt) {
    v4i kfrag = *(const v4i*)(kbase + (size_t)(kt * 16 + l15) * DMODEL);
#pragma unroll
    for (int rg = 0; rg < 4; ++rg) {
      v4i sa = __builtin_amdgcn_mfma_i32_16x16x64_i8(kfrag, qfrag[rg], z4, 0, 0, 0);
      mi[rg] = max(mi[rg], max(max(sa[0], sa[1]), max(sa[2], sa[3])));
      float e0 = __builtin_amdgcn_exp2f((float)sa[0] * alpha2);
      float e1 = __builtin_amdgcn_exp2f((float)sa[1] * alpha2);
      float e2 = __builtin_amdgcn_exp2f((float)sa[2] * alpha2);
      float e3 = __builtin_amdgcn_exp2f((float)sa[3] * alpha2);
      z[rg] += (e0 + e1) + (e2 + e3);
    }
  }
  // combine the 4 g-copies of each q-row (lanes xor 16, 32)
#pragma unroll
  for (int rg = 0; rg < 4; ++rg) {
    z[rg] += __shfl_xor(z[rg], 16, 64);
    mi[rg] = max(mi[rg], __shfl_xor(mi[rg], 16, 64));
    z[rg] += __shfl_xor(z[rg], 32, 64);
    mi[rg] = max(mi[rg], __shfl_xor(mi[rg], 32, 64));
  }
  if (lane < 16) {
#pragma unroll
    for (int rg = 0; rg < 4; ++rg) {
      zbuf[wave][rg * 16 + l15] = z[rg];
      mbuf[wave][rg * 16 + l15] = mi[rg];
    }
  }
  __syncthreads();
  if (threadIdx.x < 64) {
    int r = threadIdx.x;
    float zt = (zbuf[0][r] + zbuf[1][r]) + (zbuf[2][r] + zbuf[3][r]);
    int mt = max(max(mbuf[0][r], mbuf[1][r]), max(mbuf[2][r], mbuf[3][r]));
    float iz = 1.0f / zt;
    invz[(size_t)bh * NQ + row0 + r] = iz;
    float ma = __builtin_amdgcn_exp2f((float)mt * alpha2) * iz;  // row softmax max
    for (int off = 1; off < 64; off <<= 1)
      ma = fmaxf(ma, __shfl_xor(ma, off, 64));
    if (r == 0) atomicMax(scal + 3, __float_as_uint(ma));
  }
}

// pass 2 v2: recompute S, a_int = round(exp2(s*a2 + lc_row)) folded; wave-private
// LDS C->A transpose with NO barriers (DS pipe is in-order per wave); int8 PV.
__global__ __launch_bounds__(256) void k_pass2(
    const int8_t* __restrict__ q8, const int8_t* __restrict__ k8,
    const int8_t* __restrict__ v8t, const float* __restrict__ invz,
    const unsigned* __restrict__ scal, float* __restrict__ o) {
  __shared__ int8_t attn_lds[4][16 * 80];  // per-wave 16 rows x 64 keys, stride 80
  int bh = blockIdx.y, b = bh >> 3, h = bh & 7;
  int wave = threadIdx.x >> 6, lane = threadIdx.x & 63;
  int l15 = lane & 15, g = lane >> 4;
  int row0 = blockIdx.x * 64 + wave * 16;
  const float aq = __uint_as_float(scal[0]), ak = __uint_as_float(scal[1]);
  const float avv = __uint_as_float(scal[2]), izm = __uint_as_float(scal[3]);
  const float alpha2 = (aq * ak) * (0.125f / (127.0f * 127.0f)) * 1.44269504f;
  const float oscale = (izm / 127.0f) * (avv / 127.0f);  // delta_attn * delta_v
  const v4i z4 = {0, 0, 0, 0};
  v4i qfrag = *(const v4i*)(q8 + (size_t)(b * NQ + row0 + l15) * DMODEL + h * DH + g * 16);
  // per-row folded constant: a = exp2(s*alpha2 + lc), lc = log2(invz * 127/izm)
  const float lc = __builtin_amdgcn_logf(invz[(size_t)bh * NQ + row0 + l15] * (127.0f / izm));
  const int8_t* kbase = k8 + (size_t)b * MK * DMODEL + h * DH + g * 16;
  const int8_t* vbase = v8t + (size_t)bh * DH * MK;
  int8_t* alds = attn_lds[wave];
  v4i pacc[4] = {};

  for (int kt = 0; kt < MK / 64; ++kt) {
#pragma unroll
    for (int t = 0; t < 4; ++t) {
      int key0 = kt * 64 + t * 16;
      v4i kfrag = *(const v4i*)(kbase + (size_t)(key0 + l15) * DMODEL);
      v4i sa = __builtin_amdgcn_mfma_i32_16x16x64_i8(kfrag, qfrag, z4, 0, 0, 0);
      unsigned packed = 0;
#pragma unroll
      for (int r = 0; r < 4; ++r) {
        float a = __builtin_amdgcn_exp2f(fmaf((float)sa[r], alpha2, lc));
        int ai = __float2int_rn(a);          // a >= 0 always
        ai = ai > 127 ? 127 : ai;
        packed |= ((unsigned)ai) << (8 * r);
      }
      // C-layout: col(l15)=q-row, row(g*4+r)=key -> store at [qrow][key_local]
      *(unsigned*)(alds + l15 * 80 + t * 16 + g * 4) = packed;
    }
    // wave-private LDS; DS ops execute in-order within a wave -> no barrier
    v4i afrag = *(const v4i*)(alds + l15 * 80 + g * 16);  // A-layout read
#pragma unroll
    for (int t = 0; t < 4; ++t) {
      v4i bfrag = *(const v4i*)(vbase + (size_t)(t * 16 + l15) * MK + kt * 64 + g * 16);
      pacc[t] = __builtin_amdgcn_mfma_i32_16x16x64_i8(afrag, bfrag, pacc[t], 0, 0, 0);
    }
  }
#pragma unroll
  for (int t = 0; t < 4; ++t)
#pragma unroll
    for (int r = 0; r < 4; ++r) {
      int row = row0 + g * 4 + r;
      o[(size_t)(b * NQ + row) * DMODEL + h * DH + t * 16 + l15] =
          (float)pacc[t][r] * oscale;
    }
}

extern "C" void kernel_launch(void* const* d_in, const int* in_sizes, int n_in,
                              void* d_out, int out_size, void* d_ws, size_t ws_size,
                              hipStream_t stream) {
  (void)in_sizes; (void)n_in; (void)out_size; (void)ws_size;
  const float* x   = (const float*)d_in[0];
  const float* ctx = (const float*)d_in[1];
  const float* Wq  = (const float*)d_in[2];
  const float* Wk  = (const float*)d_in[3];
  const float* Wv  = (const float*)d_in[4];
  const float* Wo  = (const float*)d_in[5];
  const float* bo  = (const float*)d_in[6];
  float* out = (float*)d_out;

  char* ws = (char*)d_ws;
  size_t off = 0;
  auto alloc = [&](size_t bytes) {
    char* p = ws + off;
    off += (bytes + 255) & ~(size_t)255;
    return p;
  };
  unsigned* scal = (unsigned*)alloc(16);
  __bf16* Wq_t = (__bf16*)alloc((size_t)512 * 512 * 2);
  __bf16* Wk_t = (__bf16*)alloc((size_t)512 * 768 * 2);
  __bf16* Wv_t = (__bf16*)alloc((size_t)512 * 768 * 2);
  __bf16* Wo_t = (__bf16*)alloc((size_t)512 * 512 * 2);
  float* qf = (float*)alloc((size_t)BATCH * NQ * DMODEL * 4);  // later reused as o
  float* kf = (float*)alloc((size_t)BATCH * MK * DMODEL * 4);
  float* vf = (float*)alloc((size_t)BATCH * MK * DMODEL * 4);
  int8_t* q8 = (int8_t*)alloc((size_t)BATCH * NQ * DMODEL);
  int8_t* k8 = (int8_t*)alloc((size_t)BATCH * MK * DMODEL);
  int8_t* v8t = (int8_t*)alloc((size_t)BATCH * NH * DH * MK);
  float* invz = (float*)alloc((size_t)BATCH * NH * NQ * 4);
  float* o = qf;  // q_f32 dead after quantization; alias saves 16.8 MB

  k_init<<<1, 64, 0, stream>>>(scal);
  k_wtrans<<<dim3(16, 24, 4), 256, 0, stream>>>(Wq, Wk, Wv, Wo, Wq_t, Wk_t, Wv_t, Wo_t);
  k_gemm<false, true><<<dim3(64, 4), 256, 0, stream>>>(x,   Wq_t, qf, 8192, 512, 512, nullptr, scal + 0);
  k_gemm<false, true><<<dim3(16, 4), 256, 0, stream>>>(ctx, Wk_t, kf, 2048, 512, 768, nullptr, scal + 1);
  k_gemm<false, true><<<dim3(16, 4), 256, 0, stream>>>(ctx, Wv_t, vf, 2048, 512, 768, nullptr, scal + 2);
  k_quant_qk<<<5120, 256, 0, stream>>>(qf, kf, q8, k8, scal);
  k_vtrans<<<dim3(16, 16), 256, 0, stream>>>(vf, v8t, scal);
  k_pass1<<<dim3(64, 16), 256, 0, stream>>>(q8, k8, invz, scal);
  k_pass2<<<dim3(64, 16), 256, 0, stream>>>(q8, k8, v8t, invz, scal, o);
  k_gemm<true, false><<<dim3(64, 4), 256, 0, stream>>>(o, Wo_t, out, 8192, 512, 512, bo, nullptr);
}

// Round 3
// 248.763 us; speedup vs baseline: 1.2799x; 1.0053x over previous
//
#include <hip/hip_runtime.h>
#include <stdint.h>

typedef float  v4f  __attribute__((ext_vector_type(4)));
typedef int    v4i  __attribute__((ext_vector_type(4)));
typedef __bf16 v8bf __attribute__((ext_vector_type(8)));
typedef __bf16 v4bf __attribute__((ext_vector_type(4)));

#define BATCH  2
#define NQ     4096
#define MK     1024
#define DMODEL 512
#define DCTX   768
#define NH     8
#define DH     64

// scal[0]=amax_q bits, [1]=amax_k, [2]=amax_v, [3]=max(1/Z) bits (all nonneg floats)
__global__ void k_init(unsigned* scal) {
  if (threadIdx.x < 4) scal[threadIdx.x] = 0u;
}

// W[K][512] fp32 -> Wt[512][K] bf16 (so GEMM B-operand stages contiguous along K)
__global__ __launch_bounds__(256) void k_wtrans(
    const float* __restrict__ Wq, const float* __restrict__ Wk,
    const float* __restrict__ Wv, const float* __restrict__ Wo,
    __bf16* __restrict__ Wq_t, __bf16* __restrict__ Wk_t,
    __bf16* __restrict__ Wv_t, __bf16* __restrict__ Wo_t) {
  const float* src; __bf16* dst; int K;
  switch (blockIdx.z) {
    case 0:  src = Wq; dst = Wq_t; K = DMODEL; break;
    case 1:  src = Wk; dst = Wk_t; K = DCTX;   break;
    case 2:  src = Wv; dst = Wv_t; K = DCTX;   break;
    default: src = Wo; dst = Wo_t; K = DMODEL; break;
  }
  int k0 = blockIdx.y * 32;
  if (k0 >= K) return;
  int n0 = blockIdx.x * 32;
  __shared__ __bf16 tile[32][33];
  int c = threadIdx.x & 31, r0 = threadIdx.x >> 5;
  for (int i = 0; i < 4; ++i) {
    int r = r0 + i * 8;
    tile[c][r] = (__bf16)src[(size_t)(k0 + r) * DMODEL + n0 + c];
  }
  __syncthreads();
  for (int i = 0; i < 4; ++i) {
    int r = r0 + i * 8;
    dst[(size_t)(n0 + r) * K + k0 + c] = tile[r][c];
  }
}

// C[M][N] = A[M][K](f32) @ Bt[N][K](bf16)^T, 64x64 tile, BK=64, 4 waves x 32x32.
// amax target: amaxLo for output cols < 512, amaxHi for cols >= 512.
template<bool BIAS, bool AMAX>
__global__ __launch_bounds__(256, 4) void k_gemm64(
    const float* __restrict__ A, const __bf16* __restrict__ Bt,
    float* __restrict__ C, int M, int N, int K,
    const float* __restrict__ bias,
    unsigned* __restrict__ amaxLo, unsigned* __restrict__ amaxHi) {
  __shared__ __bf16 As[64 * 76];  // stride 76 -> spread banks for b128 frag reads
  __shared__ __bf16 Bs[64 * 76];
  __shared__ float redmax[4];
  const int tid = threadIdx.x;
  const int lane = tid & 63, wave = tid >> 6;
  const int l15 = lane & 15, g = lane >> 4;
  const int row0 = blockIdx.x * 64, col0 = blockIdx.y * 64;
  const int wrow = (wave >> 1) * 32, wcol = (wave & 1) * 32;

  v4f acc[2][2] = {};

  for (int k0 = 0; k0 < K; k0 += 64) {
#pragma unroll
    for (int i = 0; i < 4; ++i) {   // A: 64x64 f32 -> bf16 (16 float4 per row)
      int f = tid + 256 * i;
      int r = f >> 4, c4 = (f & 15) << 2;
      float4 av = *(const float4*)(A + (size_t)(row0 + r) * K + k0 + c4);
      v4bf ap = { (__bf16)av.x, (__bf16)av.y, (__bf16)av.z, (__bf16)av.w };
      *(v4bf*)(&As[r * 76 + c4]) = ap;
    }
#pragma unroll
    for (int i = 0; i < 2; ++i) {   // B: 64x64 bf16 (8 v8bf per row)
      int f = tid + 256 * i;
      int r = f >> 3, c8 = (f & 7) << 3;
      *(v8bf*)(&Bs[r * 76 + c8]) =
          *(const v8bf*)(Bt + (size_t)(col0 + r) * K + k0 + c8);
    }
    __syncthreads();
#pragma unroll
    for (int c = 0; c < 2; ++c) {   // two K=32 chunks, accumulation order == BK32 version
      v8bf af0 = *(const v8bf*)(&As[(wrow + l15) * 76 + c * 32 + g * 8]);
      v8bf af1 = *(const v8bf*)(&As[(wrow + 16 + l15) * 76 + c * 32 + g * 8]);
      v8bf bf0 = *(const v8bf*)(&Bs[(wcol + l15) * 76 + c * 32 + g * 8]);
      v8bf bf1 = *(const v8bf*)(&Bs[(wcol + 16 + l15) * 76 + c * 32 + g * 8]);
      acc[0][0] = __builtin_amdgcn_mfma_f32_16x16x32_bf16(af0, bf0, acc[0][0], 0, 0, 0);
      acc[0][1] = __builtin_amdgcn_mfma_f32_16x16x32_bf16(af0, bf1, acc[0][1], 0, 0, 0);
      acc[1][0] = __builtin_amdgcn_mfma_f32_16x16x32_bf16(af1, bf0, acc[1][0], 0, 0, 0);
      acc[1][1] = __builtin_amdgcn_mfma_f32_16x16x32_bf16(af1, bf1, acc[1][1], 0, 0, 0);
    }
    __syncthreads();
  }

  float lmax = 0.0f;
#pragma unroll
  for (int j = 0; j < 2; ++j) {
    int col = col0 + wcol + j * 16 + l15;
    float bv = BIAS ? bias[col] : 0.0f;
#pragma unroll
    for (int i = 0; i < 2; ++i) {
#pragma unroll
      for (int r = 0; r < 4; ++r) {
        int row = row0 + wrow + i * 16 + g * 4 + r;  // C/D: col=lane&15, row=quad*4+reg
        float cv = acc[i][j][r] + bv;
        C[(size_t)row * N + col] = cv;
        if (AMAX) lmax = fmaxf(lmax, fabsf(cv));
      }
    }
  }
  if (AMAX) {
    for (int off = 32; off > 0; off >>= 1)
      lmax = fmaxf(lmax, __shfl_xor(lmax, off, 64));
    if (lane == 0) redmax[wave] = lmax;
    __syncthreads();
    if (tid == 0) {
      float bm = fmaxf(fmaxf(redmax[0], redmax[1]), fmaxf(redmax[2], redmax[3]));
      atomicMax(col0 < 512 ? amaxLo : amaxHi, __float_as_uint(bm));
    }
  }
}

// q from qf (flat [2*4096][512]); k from kvf cols 0..511 (row stride 1024)
__global__ __launch_bounds__(256) void k_quant_qk(
    const float* __restrict__ qf, const float* __restrict__ kvf,
    int8_t* __restrict__ q8, int8_t* __restrict__ k8,
    const unsigned* __restrict__ scal) {
  const int Q4 = BATCH * NQ * DMODEL / 4;
  const int K4 = BATCH * MK * DMODEL / 4;
  int idx = blockIdx.x * 256 + threadIdx.x;
  float4 v; int8_t* dst; float s;
  if (idx < Q4) {
    v = ((const float4*)qf)[idx];
    dst = q8 + (size_t)idx * 4;
    s = 127.0f / __uint_as_float(scal[0]);
  } else {
    int j = idx - Q4;
    if (j >= K4) return;
    int r = j >> 7;             // 128 float4 per 512-wide k-row
    int c4 = (j & 127) << 2;
    v = *(const float4*)(kvf + (size_t)r * 1024 + c4);
    dst = k8 + (size_t)j * 4;   // j*4 == r*512 + c4
    s = 127.0f / __uint_as_float(scal[1]);
  }
  int a0 = __float2int_rn(v.x * s), a1 = __float2int_rn(v.y * s);
  int a2 = __float2int_rn(v.z * s), a3 = __float2int_rn(v.w * s);
  a0 = max(-128, min(127, a0)); a1 = max(-128, min(127, a1));
  a2 = max(-128, min(127, a2)); a3 = max(-128, min(127, a3));
  unsigned p = (unsigned)(a0 & 255) | ((unsigned)(a1 & 255) << 8) |
               ((unsigned)(a2 & 255) << 16) | ((unsigned)(a3 & 255) << 24);
  *(unsigned*)dst = p;
}

// v from kvf cols 512..1023 -> v8t[bh][dh][m] int8 (PV B-frags contiguous along m)
__global__ __launch_bounds__(256) void k_vtrans(
    const float* __restrict__ kvf, int8_t* __restrict__ v8t,
    const unsigned* __restrict__ scal) {
  const float s = 127.0f / __uint_as_float(scal[2]);
  int bh = blockIdx.y;
  int b = bh >> 3, h = bh & 7;
  int j0 = blockIdx.x * 64;
  __shared__ int8_t tile[64][80];
  int t = threadIdx.x;
  int j = t >> 2, dh0 = (t & 3) << 4;
  const float* src = kvf + (size_t)(b * MK + j0 + j) * 1024 + 512 + h * DH + dh0;
#pragma unroll
  for (int i = 0; i < 16; i += 4) {
    float4 v = *(const float4*)(src + i);
    int a0 = __float2int_rn(v.x * s), a1 = __float2int_rn(v.y * s);
    int a2 = __float2int_rn(v.z * s), a3 = __float2int_rn(v.w * s);
    tile[dh0 + i + 0][j] = (int8_t)max(-128, min(127, a0));
    tile[dh0 + i + 1][j] = (int8_t)max(-128, min(127, a1));
    tile[dh0 + i + 2][j] = (int8_t)max(-128, min(127, a2));
    tile[dh0 + i + 3][j] = (int8_t)max(-128, min(127, a3));
  }
  __syncthreads();
  int dh = t >> 2, jb = (t & 3) << 4;
  v4i val = *(const v4i*)(&tile[dh][jb]);
  *(v4i*)(v8t + (size_t)(bh * DH + dh) * MK + j0 + jb) = val;
}

// pass 1: wave w handles keys [w*256,(w+1)*256) for all 64 q-rows.
// No-max z accumulation (scores tiny; exp2 can't overflow): z = sum exp2(s*a2).
__global__ __launch_bounds__(256) void k_pass1(
    const int8_t* __restrict__ q8, const int8_t* __restrict__ k8,
    float* __restrict__ invz, unsigned* __restrict__ scal) {
  __shared__ float zbuf[4][64];
  __shared__ int   mbuf[4][64];
  int bh = blockIdx.y, b = bh >> 3, h = bh & 7;
  int wave = threadIdx.x >> 6, lane = threadIdx.x & 63;
  int l15 = lane & 15, g = lane >> 4;
  int row0 = blockIdx.x * 64;
  const float aq = __uint_as_float(scal[0]), ak = __uint_as_float(scal[1]);
  const float alpha2 = (aq * ak) * (0.125f / (127.0f * 127.0f)) * 1.44269504f;
  const v4i z4 = {0, 0, 0, 0};
  v4i qfrag[4];
#pragma unroll
  for (int rg = 0; rg < 4; ++rg)
    qfrag[rg] = *(const v4i*)(q8 + (size_t)(b * NQ + row0 + rg * 16 + l15) * DMODEL + h * DH + g * 16);
  const int8_t* kbase = k8 + (size_t)b * MK * DMODEL + h * DH + g * 16 +
                        (size_t)wave * 256 * DMODEL;
  float z[4] = {0.f, 0.f, 0.f, 0.f};
  int mi[4] = {-(1 << 30), -(1 << 30), -(1 << 30), -(1 << 30)};
  for (int kt = 0; kt < 16; ++kt) {
    v4i kfrag = *(const v4i*)(kbase + (size_t)(kt * 16 + l15) * DMODEL);
#pragma unroll
    for (int rg = 0; rg < 4; ++rg) {
      v4i sa = __builtin_amdgcn_mfma_i32_16x16x64_i8(kfrag, qfrag[rg], z4, 0, 0, 0);
      mi[rg] = max(mi[rg], max(max(sa[0], sa[1]), max(sa[2], sa[3])));
      float e0 = __builtin_amdgcn_exp2f((float)sa[0] * alpha2);
      float e1 = __builtin_amdgcn_exp2f((float)sa[1] * alpha2);
      float e2 = __builtin_amdgcn_exp2f((float)sa[2] * alpha2);
      float e3 = __builtin_amdgcn_exp2f((float)sa[3] * alpha2);
      z[rg] += (e0 + e1) + (e2 + e3);
    }
  }
#pragma unroll
  for (int rg = 0; rg < 4; ++rg) {
    z[rg] += __shfl_xor(z[rg], 16, 64);
    mi[rg] = max(mi[rg], __shfl_xor(mi[rg], 16, 64));
    z[rg] += __shfl_xor(z[rg], 32, 64);
    mi[rg] = max(mi[rg], __shfl_xor(mi[rg], 32, 64));
  }
  if (lane < 16) {
#pragma unroll
    for (int rg = 0; rg < 4; ++rg) {
      zbuf[wave][rg * 16 + l15] = z[rg];
      mbuf[wave][rg * 16 + l15] = mi[rg];
    }
  }
  __syncthreads();
  if (threadIdx.x < 64) {
    int r = threadIdx.x;
    float zt = (zbuf[0][r] + zbuf[1][r]) + (zbuf[2][r] + zbuf[3][r]);
    int mt = max(max(mbuf[0][r], mbuf[1][r]), max(mbuf[2][r], mbuf[3][r]));
    float iz = 1.0f / zt;
    invz[(size_t)bh * NQ + row0 + r] = iz;
    float ma = __builtin_amdgcn_exp2f((float)mt * alpha2) * iz;  // row softmax max
    for (int off = 1; off < 64; off <<= 1)
      ma = fmaxf(ma, __shfl_xor(ma, off, 64));
    if (r == 0) atomicMax(scal + 3, __float_as_uint(ma));
  }
}

// pass 2 v3: 128-key iterations (2 staggered 64-key subtiles), kfrag loaded one
// iteration ahead, magic-add RNE quantization (no clamp needed: a <= 127*(1+3e-6)),
// wave-private LDS C->A transpose with no barriers, int8 PV.
__global__ __launch_bounds__(256, 3) void k_pass2(
    const int8_t* __restrict__ q8, const int8_t* __restrict__ k8,
    const int8_t* __restrict__ v8t, const float* __restrict__ invz,
    const unsigned* __restrict__ scal, float* __restrict__ o) {
  __shared__ __align__(16) int8_t attn_lds[4][2][16 * 80];
  int bh = blockIdx.y, b = bh >> 3, h = bh & 7;
  int wave = threadIdx.x >> 6, lane = threadIdx.x & 63;
  int l15 = lane & 15, g = lane >> 4;
  int row0 = blockIdx.x * 64 + wave * 16;
  const float aq = __uint_as_float(scal[0]), ak = __uint_as_float(scal[1]);
  const float avv = __uint_as_float(scal[2]), izm = __uint_as_float(scal[3]);
  const float alpha2 = (aq * ak) * (0.125f / (127.0f * 127.0f)) * 1.44269504f;
  const float oscale = (izm / 127.0f) * (avv / 127.0f);  // delta_attn * delta_v
  const float MAGIC = 12582912.0f;                       // 1.5 * 2^23
  const v4i z4 = {0, 0, 0, 0};
  v4i qfrag = *(const v4i*)(q8 + (size_t)(b * NQ + row0 + l15) * DMODEL + h * DH + g * 16);
  // per-row folded constant: a = exp2(s*alpha2 + lc), lc = log2(invz * 127/izm)
  const float lc = __builtin_amdgcn_logf(invz[(size_t)bh * NQ + row0 + l15] * (127.0f / izm));
  const int8_t* kbase = k8 + (size_t)b * MK * DMODEL + h * DH + g * 16;
  const int8_t* vbase = v8t + (size_t)bh * DH * MK;
  int8_t* alds0 = attn_lds[wave][0];
  int8_t* alds1 = attn_lds[wave][1];
  v4i pacc[4] = {};

  v4i kf[8];
#pragma unroll
  for (int t = 0; t < 8; ++t)
    kf[t] = *(const v4i*)(kbase + (size_t)(t * 16 + l15) * DMODEL);

  for (int kt = 0; kt < 8; ++kt) {
    // PV B-frags for this iteration (needed late; L2 latency hidden under VALU)
    v4i bf[8];
#pragma unroll
    for (int p = 0; p < 8; ++p) {
      int t = p & 3, u = p >> 2;
      bf[p] = *(const v4i*)(vbase + (size_t)(t * 16 + l15) * MK + kt * 128 + u * 64 + g * 16);
    }
    // QK: 8 independent MFMAs
    v4i sa[8];
#pragma unroll
    for (int p = 0; p < 8; ++p)
      sa[p] = __builtin_amdgcn_mfma_i32_16x16x64_i8(kf[p], qfrag, z4, 0, 0, 0);
    // prefetch next iteration's kfrags
    if (kt < 7) {
#pragma unroll
      for (int t = 0; t < 8; ++t)
        kf[t] = *(const v4i*)(kbase + (size_t)((kt + 1) * 128 + t * 16 + l15) * DMODEL);
    }
    // quantize + pack + LDS (subtile u=0 then u=1; reads staggered below)
#pragma unroll
    for (int u = 0; u < 2; ++u) {
      int8_t* alds = u ? alds1 : alds0;
#pragma unroll
      for (int t = 0; t < 4; ++t) {
        v4i s = sa[u * 4 + t];
        float f0 = __builtin_amdgcn_exp2f(fmaf((float)s[0], alpha2, lc)) + MAGIC;
        float f1 = __builtin_amdgcn_exp2f(fmaf((float)s[1], alpha2, lc)) + MAGIC;
        float f2 = __builtin_amdgcn_exp2f(fmaf((float)s[2], alpha2, lc)) + MAGIC;
        float f3 = __builtin_amdgcn_exp2f(fmaf((float)s[3], alpha2, lc)) + MAGIC;
        unsigned packed = (__float_as_uint(f0) & 255u) |
                          ((__float_as_uint(f1) & 255u) << 8) |
                          ((__float_as_uint(f2) & 255u) << 16) |
                          (__float_as_uint(f3) << 24);
        // C-layout: col(l15)=q-row, row(g*4+r)=key -> store at [qrow][key_local]
        *(unsigned*)(alds + l15 * 80 + t * 16 + g * 4) = packed;
      }
    }
    // PV (wave-private LDS, DS pipe in-order per wave -> no barrier)
#pragma unroll
    for (int u = 0; u < 2; ++u) {
      v4i afrag = *(const v4i*)((u ? alds1 : alds0) + l15 * 80 + g * 16);
#pragma unroll
      for (int t = 0; t < 4; ++t)
        pacc[t] = __builtin_amdgcn_mfma_i32_16x16x64_i8(afrag, bf[u * 4 + t], pacc[t], 0, 0, 0);
    }
  }
#pragma unroll
  for (int t = 0; t < 4; ++t)
#pragma unroll
    for (int r = 0; r < 4; ++r) {
      int row = row0 + g * 4 + r;
      o[(size_t)(b * NQ + row) * DMODEL + h * DH + t * 16 + l15] =
          (float)pacc[t][r] * oscale;
    }
}

extern "C" void kernel_launch(void* const* d_in, const int* in_sizes, int n_in,
                              void* d_out, int out_size, void* d_ws, size_t ws_size,
                              hipStream_t stream) {
  (void)in_sizes; (void)n_in; (void)out_size; (void)ws_size;
  const float* x   = (const float*)d_in[0];
  const float* ctx = (const float*)d_in[1];
  const float* Wq  = (const float*)d_in[2];
  const float* Wk  = (const float*)d_in[3];
  const float* Wv  = (const float*)d_in[4];
  const float* Wo  = (const float*)d_in[5];
  const float* bo  = (const float*)d_in[6];
  float* out = (float*)d_out;

  char* ws = (char*)d_ws;
  size_t off = 0;
  auto alloc = [&](size_t bytes) {
    char* p = ws + off;
    off += (bytes + 255) & ~(size_t)255;
    return p;
  };
  unsigned* scal = (unsigned*)alloc(16);
  __bf16* Wq_t = (__bf16*)alloc((size_t)512 * 512 * 2);
  __bf16* Wk_t = (__bf16*)alloc((size_t)512 * 768 * 2);  // contiguous with Wv_t:
  __bf16* Wv_t = (__bf16*)alloc((size_t)512 * 768 * 2);  //   B for fused kv GEMM (N=1024)
  __bf16* Wo_t = (__bf16*)alloc((size_t)512 * 512 * 2);
  float* qf  = (float*)alloc((size_t)BATCH * NQ * DMODEL * 4);   // later reused as o
  float* kvf = (float*)alloc((size_t)BATCH * MK * 1024 * 4);     // [2048][1024]: k | v
  int8_t* q8 = (int8_t*)alloc((size_t)BATCH * NQ * DMODEL);
  int8_t* k8 = (int8_t*)alloc((size_t)BATCH * MK * DMODEL);
  int8_t* v8t = (int8_t*)alloc((size_t)BATCH * NH * DH * MK);
  float* invz = (float*)alloc((size_t)BATCH * NH * NQ * 4);
  float* o = qf;  // q_f32 dead after quantization

  k_init<<<1, 64, 0, stream>>>(scal);
  k_wtrans<<<dim3(16, 24, 4), 256, 0, stream>>>(Wq, Wk, Wv, Wo, Wq_t, Wk_t, Wv_t, Wo_t);
  k_gemm64<false, true><<<dim3(128, 8), 256, 0, stream>>>(
      x, Wq_t, qf, 8192, 512, 512, nullptr, scal + 0, scal + 0);
  k_gemm64<false, true><<<dim3(32, 16), 256, 0, stream>>>(
      ctx, Wk_t, kvf, 2048, 1024, 768, nullptr, scal + 1, scal + 2);
  k_quant_qk<<<5120, 256, 0, stream>>>(qf, kvf, q8, k8, scal);
  k_vtrans<<<dim3(16, 16), 256, 0, stream>>>(kvf, v8t, scal);
  k_pass1<<<dim3(64, 16), 256, 0, stream>>>(q8, k8, invz, scal);
  k_pass2<<<dim3(64, 16), 256, 0, stream>>>(q8, k8, v8t, invz, scal, o);
  k_gemm64<true, false><<<dim3(128, 8), 256, 0, stream>>>(
      o, Wo_t, out, 8192, 512, 512, bo, nullptr, nullptr);
}

// Round 4
// 215.700 us; speedup vs baseline: 1.4760x; 1.1533x over previous
//
#include <hip/hip_runtime.h>
#include <stdint.h>

typedef float  v4f  __attribute__((ext_vector_type(4)));
typedef int    v4i  __attribute__((ext_vector_type(4)));
typedef __bf16 v8bf __attribute__((ext_vector_type(8)));
typedef __bf16 v4bf __attribute__((ext_vector_type(4)));

#define BATCH  2
#define NQ     4096
#define MK     1024
#define DMODEL 512
#define DCTX   768
#define NH     8
#define DH     64

// scal[0]=amax_q bits, [1]=amax_k, [2]=amax_v, [3]=max(1/Z) bits (all nonneg floats)
__global__ void k_init(unsigned* scal) {
  if (threadIdx.x < 4) scal[threadIdx.x] = 0u;
}

// W[K][512] fp32 -> Wt[512][K] bf16 (so GEMM B-operand stages contiguous along K)
__global__ __launch_bounds__(256) void k_wtrans(
    const float* __restrict__ Wq, const float* __restrict__ Wk,
    const float* __restrict__ Wv, const float* __restrict__ Wo,
    __bf16* __restrict__ Wq_t, __bf16* __restrict__ Wk_t,
    __bf16* __restrict__ Wv_t, __bf16* __restrict__ Wo_t) {
  const float* src; __bf16* dst; int K;
  switch (blockIdx.z) {
    case 0:  src = Wq; dst = Wq_t; K = DMODEL; break;
    case 1:  src = Wk; dst = Wk_t; K = DCTX;   break;
    case 2:  src = Wv; dst = Wv_t; K = DCTX;   break;
    default: src = Wo; dst = Wo_t; K = DMODEL; break;
  }
  int k0 = blockIdx.y * 32;
  if (k0 >= K) return;
  int n0 = blockIdx.x * 32;
  __shared__ __bf16 tile[32][33];
  int c = threadIdx.x & 31, r0 = threadIdx.x >> 5;
  for (int i = 0; i < 4; ++i) {
    int r = r0 + i * 8;
    tile[c][r] = (__bf16)src[(size_t)(k0 + r) * DMODEL + n0 + c];
  }
  __syncthreads();
  for (int i = 0; i < 4; ++i) {
    int r = r0 + i * 8;
    dst[(size_t)(n0 + r) * K + k0 + c] = tile[r][c];
  }
}

// C[M][N] = A[M][K](f32) @ Bt[N][K](bf16)^T, 64x64 tile, BK=64, 4 waves x 32x32.
// amax target: amaxLo for output cols < 512, amaxHi for cols >= 512.
template<bool BIAS, bool AMAX>
__global__ __launch_bounds__(256, 4) void k_gemm64(
    const float* __restrict__ A, const __bf16* __restrict__ Bt,
    float* __restrict__ C, int M, int N, int K,
    const float* __restrict__ bias,
    unsigned* __restrict__ amaxLo, unsigned* __restrict__ amaxHi) {
  __shared__ __bf16 As[64 * 76];  // stride 76 -> spread banks for b128 frag reads
  __shared__ __bf16 Bs[64 * 76];
  __shared__ float redmax[4];
  const int tid = threadIdx.x;
  const int lane = tid & 63, wave = tid >> 6;
  const int l15 = lane & 15, g = lane >> 4;
  const int row0 = blockIdx.x * 64, col0 = blockIdx.y * 64;
  const int wrow = (wave >> 1) * 32, wcol = (wave & 1) * 32;

  v4f acc[2][2] = {};

  for (int k0 = 0; k0 < K; k0 += 64) {
#pragma unroll
    for (int i = 0; i < 4; ++i) {   // A: 64x64 f32 -> bf16 (16 float4 per row)
      int f = tid + 256 * i;
      int r = f >> 4, c4 = (f & 15) << 2;
      float4 av = *(const float4*)(A + (size_t)(row0 + r) * K + k0 + c4);
      v4bf ap = { (__bf16)av.x, (__bf16)av.y, (__bf16)av.z, (__bf16)av.w };
      *(v4bf*)(&As[r * 76 + c4]) = ap;
    }
#pragma unroll
    for (int i = 0; i < 2; ++i) {   // B: 64x64 bf16 (8 v8bf per row)
      int f = tid + 256 * i;
      int r = f >> 3, c8 = (f & 7) << 3;
      *(v8bf*)(&Bs[r * 76 + c8]) =
          *(const v8bf*)(Bt + (size_t)(col0 + r) * K + k0 + c8);
    }
    __syncthreads();
#pragma unroll
    for (int c = 0; c < 2; ++c) {   // two K=32 chunks, accumulation order == BK32 version
      v8bf af0 = *(const v8bf*)(&As[(wrow + l15) * 76 + c * 32 + g * 8]);
      v8bf af1 = *(const v8bf*)(&As[(wrow + 16 + l15) * 76 + c * 32 + g * 8]);
      v8bf bf0 = *(const v8bf*)(&Bs[(wcol + l15) * 76 + c * 32 + g * 8]);
      v8bf bf1 = *(const v8bf*)(&Bs[(wcol + 16 + l15) * 76 + c * 32 + g * 8]);
      acc[0][0] = __builtin_amdgcn_mfma_f32_16x16x32_bf16(af0, bf0, acc[0][0], 0, 0, 0);
      acc[0][1] = __builtin_amdgcn_mfma_f32_16x16x32_bf16(af0, bf1, acc[0][1], 0, 0, 0);
      acc[1][0] = __builtin_amdgcn_mfma_f32_16x16x32_bf16(af1, bf0, acc[1][0], 0, 0, 0);
      acc[1][1] = __builtin_amdgcn_mfma_f32_16x16x32_bf16(af1, bf1, acc[1][1], 0, 0, 0);
    }
    __syncthreads();
  }

  float lmax = 0.0f;
#pragma unroll
  for (int j = 0; j < 2; ++j) {
    int col = col0 + wcol + j * 16 + l15;
    float bv = BIAS ? bias[col] : 0.0f;
#pragma unroll
    for (int i = 0; i < 2; ++i) {
#pragma unroll
      for (int r = 0; r < 4; ++r) {
        int row = row0 + wrow + i * 16 + g * 4 + r;  // C/D: col=lane&15, row=quad*4+reg
        float cv = acc[i][j][r] + bv;
        C[(size_t)row * N + col] = cv;
        if (AMAX) lmax = fmaxf(lmax, fabsf(cv));
      }
    }
  }
  if (AMAX) {
    for (int off = 32; off > 0; off >>= 1)
      lmax = fmaxf(lmax, __shfl_xor(lmax, off, 64));
    if (lane == 0) redmax[wave] = lmax;
    __syncthreads();
    if (tid == 0) {
      float bm = fmaxf(fmaxf(redmax[0], redmax[1]), fmaxf(redmax[2], redmax[3]));
      atomicMax(col0 < 512 ? amaxLo : amaxHi, __float_as_uint(bm));
    }
  }
}

// q from qf (flat [2*4096][512]); k from kvf cols 0..511 (row stride 1024)
__global__ __launch_bounds__(256) void k_quant_qk(
    const float* __restrict__ qf, const float* __restrict__ kvf,
    int8_t* __restrict__ q8, int8_t* __restrict__ k8,
    const unsigned* __restrict__ scal) {
  const int Q4 = BATCH * NQ * DMODEL / 4;
  const int K4 = BATCH * MK * DMODEL / 4;
  int idx = blockIdx.x * 256 + threadIdx.x;
  float4 v; int8_t* dst; float s;
  if (idx < Q4) {
    v = ((const float4*)qf)[idx];
    dst = q8 + (size_t)idx * 4;
    s = 127.0f / __uint_as_float(scal[0]);
  } else {
    int j = idx - Q4;
    if (j >= K4) return;
    int r = j >> 7;             // 128 float4 per 512-wide k-row
    int c4 = (j & 127) << 2;
    v = *(const float4*)(kvf + (size_t)r * 1024 + c4);
    dst = k8 + (size_t)j * 4;   // j*4 == r*512 + c4
    s = 127.0f / __uint_as_float(scal[1]);
  }
  int a0 = __float2int_rn(v.x * s), a1 = __float2int_rn(v.y * s);
  int a2 = __float2int_rn(v.z * s), a3 = __float2int_rn(v.w * s);
  a0 = max(-128, min(127, a0)); a1 = max(-128, min(127, a1));
  a2 = max(-128, min(127, a2)); a3 = max(-128, min(127, a3));
  unsigned p = (unsigned)(a0 & 255) | ((unsigned)(a1 & 255) << 8) |
               ((unsigned)(a2 & 255) << 16) | ((unsigned)(a3 & 255) << 24);
  *(unsigned*)dst = p;
}

// v from kvf cols 512..1023 -> v8t[bh][dh][m] int8 (PV B-frags contiguous along m)
__global__ __launch_bounds__(256) void k_vtrans(
    const float* __restrict__ kvf, int8_t* __restrict__ v8t,
    const unsigned* __restrict__ scal) {
  const float s = 127.0f / __uint_as_float(scal[2]);
  int bh = blockIdx.y;
  int b = bh >> 3, h = bh & 7;
  int j0 = blockIdx.x * 64;
  __shared__ int8_t tile[64][80];
  int t = threadIdx.x;
  int j = t >> 2, dh0 = (t & 3) << 4;
  const float* src = kvf + (size_t)(b * MK + j0 + j) * 1024 + 512 + h * DH + dh0;
#pragma unroll
  for (int i = 0; i < 16; i += 4) {
    float4 v = *(const float4*)(src + i);
    int a0 = __float2int_rn(v.x * s), a1 = __float2int_rn(v.y * s);
    int a2 = __float2int_rn(v.z * s), a3 = __float2int_rn(v.w * s);
    tile[dh0 + i + 0][j] = (int8_t)max(-128, min(127, a0));
    tile[dh0 + i + 1][j] = (int8_t)max(-128, min(127, a1));
    tile[dh0 + i + 2][j] = (int8_t)max(-128, min(127, a2));
    tile[dh0 + i + 3][j] = (int8_t)max(-128, min(127, a3));
  }
  __syncthreads();
  int dh = t >> 2, jb = (t & 3) << 4;
  v4i val = *(const v4i*)(&tile[dh][jb]);
  *(v4i*)(v8t + (size_t)(bh * DH + dh) * MK + j0 + jb) = val;
}

// pass 1 v3: wave w owns keys [w*256,(w+1)*256); its k-quarter is REGISTER-RESIDENT
// (16 v4i loaded once -> no in-loop global loads). Summation tree identical to v2.
__global__ __launch_bounds__(256, 4) void k_pass1(
    const int8_t* __restrict__ q8, const int8_t* __restrict__ k8,
    float* __restrict__ invz, unsigned* __restrict__ scal) {
  __shared__ float zbuf[4][64];
  __shared__ int   mbuf[4][64];
  int bh = blockIdx.y, b = bh >> 3, h = bh & 7;
  int wave = threadIdx.x >> 6, lane = threadIdx.x & 63;
  int l15 = lane & 15, g = lane >> 4;
  int row0 = blockIdx.x * 64;
  const float aq = __uint_as_float(scal[0]), ak = __uint_as_float(scal[1]);
  const float alpha2 = (aq * ak) * (0.125f / (127.0f * 127.0f)) * 1.44269504f;
  const v4i z4 = {0, 0, 0, 0};
  v4i qfrag[4];
#pragma unroll
  for (int rg = 0; rg < 4; ++rg)
    qfrag[rg] = *(const v4i*)(q8 + (size_t)(b * NQ + row0 + rg * 16 + l15) * DMODEL + h * DH + g * 16);
  const int8_t* kbase = k8 + (size_t)b * MK * DMODEL + h * DH + g * 16 +
                        (size_t)wave * 256 * DMODEL;
  v4i kf[16];
#pragma unroll
  for (int i = 0; i < 16; ++i)
    kf[i] = *(const v4i*)(kbase + (size_t)(i * 16 + l15) * DMODEL);

  float z[4] = {0.f, 0.f, 0.f, 0.f};
  int mi[4] = {-(1 << 30), -(1 << 30), -(1 << 30), -(1 << 30)};
#pragma unroll
  for (int kt = 0; kt < 16; ++kt) {
#pragma unroll
    for (int rg = 0; rg < 4; ++rg) {
      v4i sa = __builtin_amdgcn_mfma_i32_16x16x64_i8(kf[kt], qfrag[rg], z4, 0, 0, 0);
      mi[rg] = max(mi[rg], max(max(sa[0], sa[1]), max(sa[2], sa[3])));
      float e0 = __builtin_amdgcn_exp2f((float)sa[0] * alpha2);
      float e1 = __builtin_amdgcn_exp2f((float)sa[1] * alpha2);
      float e2 = __builtin_amdgcn_exp2f((float)sa[2] * alpha2);
      float e3 = __builtin_amdgcn_exp2f((float)sa[3] * alpha2);
      z[rg] += (e0 + e1) + (e2 + e3);
    }
  }
#pragma unroll
  for (int rg = 0; rg < 4; ++rg) {
    z[rg] += __shfl_xor(z[rg], 16, 64);
    mi[rg] = max(mi[rg], __shfl_xor(mi[rg], 16, 64));
    z[rg] += __shfl_xor(z[rg], 32, 64);
    mi[rg] = max(mi[rg], __shfl_xor(mi[rg], 32, 64));
  }
  if (lane < 16) {
#pragma unroll
    for (int rg = 0; rg < 4; ++rg) {
      zbuf[wave][rg * 16 + l15] = z[rg];
      mbuf[wave][rg * 16 + l15] = mi[rg];
    }
  }
  __syncthreads();
  if (threadIdx.x < 64) {
    int r = threadIdx.x;
    float zt = (zbuf[0][r] + zbuf[1][r]) + (zbuf[2][r] + zbuf[3][r]);
    int mt = max(max(mbuf[0][r], mbuf[1][r]), max(mbuf[2][r], mbuf[3][r]));
    float iz = 1.0f / zt;
    invz[(size_t)bh * NQ + row0 + r] = iz;
    float ma = __builtin_amdgcn_exp2f((float)mt * alpha2) * iz;  // row softmax max
    for (int off = 1; off < 64; off <<= 1)
      ma = fmaxf(ma, __shfl_xor(ma, off, 64));
    if (r == 0) atomicMax(scal + 3, __float_as_uint(ma));
  }
}

// pass 2 v4: wave w owns keys [w*256,(w+1)*256) for ALL 64 block q-rows; its
// k-quarter (16 v4i) and v-quarter (16 v4i) are REGISTER-RESIDENT -> zero global
// loads inside the compute loop (the R3 latency serialization came from the
// compiler sinking loads to their uses; persistent live ranges prevent that).
// Partial int32 PV accumulators are reduced across the 4 waves via LDS (exact).
__global__ __launch_bounds__(256, 2) void k_pass2(
    const int8_t* __restrict__ q8, const int8_t* __restrict__ k8,
    const int8_t* __restrict__ v8t, const float* __restrict__ invz,
    const unsigned* __restrict__ scal, float* __restrict__ o) {
  __shared__ __align__(16) int8_t attn_lds[4][16 * 80];  // 5 KB, wave-private
  __shared__ __align__(16) int redbuf[16][64][4];        // 16 KB cross-wave reduce
  int bh = blockIdx.y, b = bh >> 3, h = bh & 7;
  int wave = threadIdx.x >> 6, lane = threadIdx.x & 63;
  int l15 = lane & 15, g = lane >> 4;
  int row0 = blockIdx.x * 64;
  int key0 = wave * 256;
  const float aq = __uint_as_float(scal[0]), ak = __uint_as_float(scal[1]);
  const float avv = __uint_as_float(scal[2]), izm = __uint_as_float(scal[3]);
  const float alpha2 = (aq * ak) * (0.125f / (127.0f * 127.0f)) * 1.44269504f;
  const float oscale = (izm / 127.0f) * (avv / 127.0f);  // delta_attn * delta_v
  const float MAGIC = 12582912.0f;                       // 1.5 * 2^23
  const v4i z4 = {0, 0, 0, 0};

  v4i qfrag[4];
  float lc[4];
#pragma unroll
  for (int rg = 0; rg < 4; ++rg) {
    qfrag[rg] = *(const v4i*)(q8 + (size_t)(b * NQ + row0 + rg * 16 + l15) * DMODEL + h * DH + g * 16);
    // a = exp2(s*alpha2 + lc), lc = log2(invz * 127/izm), per q-row (row = rg*16+l15)
    lc[rg] = __builtin_amdgcn_logf(invz[(size_t)bh * NQ + row0 + rg * 16 + l15] * (127.0f / izm));
  }
  const int8_t* kbase = k8 + (size_t)(b * MK + key0) * DMODEL + h * DH + g * 16;
  v4i kf[16];
#pragma unroll
  for (int i = 0; i < 16; ++i)
    kf[i] = *(const v4i*)(kbase + (size_t)(i * 16 + l15) * DMODEL);
  const int8_t* vbase = v8t + (size_t)bh * DH * MK + key0 + g * 16;
  v4i vf[16];
#pragma unroll
  for (int d = 0; d < 4; ++d)
#pragma unroll
    for (int c = 0; c < 4; ++c)
      vf[d * 4 + c] = *(const v4i*)(vbase + (size_t)(d * 16 + l15) * MK + c * 64);

  v4i pacc[16] = {};
  int8_t* alds = attn_lds[wave];

#pragma unroll
  for (int rg = 0; rg < 4; ++rg) {
    const float lcr = lc[rg];
#pragma unroll
    for (int c = 0; c < 4; ++c) {
#pragma unroll
      for (int t = 0; t < 4; ++t) {
        v4i sa = __builtin_amdgcn_mfma_i32_16x16x64_i8(kf[c * 4 + t], qfrag[rg], z4, 0, 0, 0);
        float f0 = __builtin_amdgcn_exp2f(fmaf((float)sa[0], alpha2, lcr)) + MAGIC;
        float f1 = __builtin_amdgcn_exp2f(fmaf((float)sa[1], alpha2, lcr)) + MAGIC;
        float f2 = __builtin_amdgcn_exp2f(fmaf((float)sa[2], alpha2, lcr)) + MAGIC;
        float f3 = __builtin_amdgcn_exp2f(fmaf((float)sa[3], alpha2, lcr)) + MAGIC;
        unsigned packed = (__float_as_uint(f0) & 255u) |
                          ((__float_as_uint(f1) & 255u) << 8) |
                          ((__float_as_uint(f2) & 255u) << 16) |
                          (__float_as_uint(f3) << 24);
        // C-layout: col(l15)=q-row, row(g*4+r)=key -> store at [qrow][key_local]
        *(unsigned*)(alds + l15 * 80 + t * 16 + g * 4) = packed;
      }
      // wave-private LDS; DS pipe in-order per wave -> no barrier
      v4i afrag = *(const v4i*)(alds + l15 * 80 + g * 16);  // A-layout read
#pragma unroll
      for (int d = 0; d < 4; ++d)
        pacc[rg * 4 + d] = __builtin_amdgcn_mfma_i32_16x16x64_i8(afrag, vf[d * 4 + c], pacc[rg * 4 + d], 0, 0, 0);
    }
  }

  // cross-wave reduction of key-partials + store (exact int32 sums)
  const int dtid = threadIdx.x >> 6, ltid = threadIdx.x & 63;
  float* obase = o + (size_t)(b * NQ + row0) * DMODEL + h * DH;
#pragma unroll
  for (int rg = 0; rg < 4; ++rg) {
    __syncthreads();
#pragma unroll
    for (int d = 0; d < 4; ++d)
      *(v4i*)(&redbuf[wave * 4 + d][lane][0]) = pacc[rg * 4 + d];
    __syncthreads();
    v4i s0 = *(const v4i*)(&redbuf[dtid][ltid][0]);
    v4i s1 = *(const v4i*)(&redbuf[4 + dtid][ltid][0]);
    v4i s2 = *(const v4i*)(&redbuf[8 + dtid][ltid][0]);
    v4i s3 = *(const v4i*)(&redbuf[12 + dtid][ltid][0]);
    v4i sum = (s0 + s1) + (s2 + s3);
#pragma unroll
    for (int r = 0; r < 4; ++r) {
      int row = rg * 16 + (ltid >> 4) * 4 + r;
      obase[(size_t)row * DMODEL + dtid * 16 + (ltid & 15)] = (float)sum[r] * oscale;
    }
  }
}

extern "C" void kernel_launch(void* const* d_in, const int* in_sizes, int n_in,
                              void* d_out, int out_size, void* d_ws, size_t ws_size,
                              hipStream_t stream) {
  (void)in_sizes; (void)n_in; (void)out_size; (void)ws_size;
  const float* x   = (const float*)d_in[0];
  const float* ctx = (const float*)d_in[1];
  const float* Wq  = (const float*)d_in[2];
  const float* Wk  = (const float*)d_in[3];
  const float* Wv  = (const float*)d_in[4];
  const float* Wo  = (const float*)d_in[5];
  const float* bo  = (const float*)d_in[6];
  float* out = (float*)d_out;

  char* ws = (char*)d_ws;
  size_t off = 0;
  auto alloc = [&](size_t bytes) {
    char* p = ws + off;
    off += (bytes + 255) & ~(size_t)255;
    return p;
  };
  unsigned* scal = (unsigned*)alloc(16);
  __bf16* Wq_t = (__bf16*)alloc((size_t)512 * 512 * 2);
  __bf16* Wk_t = (__bf16*)alloc((size_t)512 * 768 * 2);  // contiguous with Wv_t:
  __bf16* Wv_t = (__bf16*)alloc((size_t)512 * 768 * 2);  //   B for fused kv GEMM (N=1024)
  __bf16* Wo_t = (__bf16*)alloc((size_t)512 * 512 * 2);
  float* qf  = (float*)alloc((size_t)BATCH * NQ * DMODEL * 4);   // later reused as o
  float* kvf = (float*)alloc((size_t)BATCH * MK * 1024 * 4);     // [2048][1024]: k | v
  int8_t* q8 = (int8_t*)alloc((size_t)BATCH * NQ * DMODEL);
  int8_t* k8 = (int8_t*)alloc((size_t)BATCH * MK * DMODEL);
  int8_t* v8t = (int8_t*)alloc((size_t)BATCH * NH * DH * MK);
  float* invz = (float*)alloc((size_t)BATCH * NH * NQ * 4);
  float* o = qf;  // q_f32 dead after quantization

  k_init<<<1, 64, 0, stream>>>(scal);
  k_wtrans<<<dim3(16, 24, 4), 256, 0, stream>>>(Wq, Wk, Wv, Wo, Wq_t, Wk_t, Wv_t, Wo_t);
  k_gemm64<false, true><<<dim3(128, 8), 256, 0, stream>>>(
      x, Wq_t, qf, 8192, 512, 512, nullptr, scal + 0, scal + 0);
  k_gemm64<false, true><<<dim3(32, 16), 256, 0, stream>>>(
      ctx, Wk_t, kvf, 2048, 1024, 768, nullptr, scal + 1, scal + 2);
  k_quant_qk<<<5120, 256, 0, stream>>>(qf, kvf, q8, k8, scal);
  k_vtrans<<<dim3(16, 16), 256, 0, stream>>>(kvf, v8t, scal);
  k_pass1<<<dim3(64, 16), 256, 0, stream>>>(q8, k8, invz, scal);
  k_pass2<<<dim3(64, 16), 256, 0, stream>>>(q8, k8, v8t, invz, scal, o);
  k_gemm64<true, false><<<dim3(128, 8), 256, 0, stream>>>(
      o, Wo_t, out, 8192, 512, 512, bo, nullptr, nullptr);
}

// Round 5
// 210.004 us; speedup vs baseline: 1.5161x; 1.0271x over previous
//
#include <hip/hip_runtime.h>
#include <stdint.h>

typedef float  v4f  __attribute__((ext_vector_type(4)));
typedef int    v4i  __attribute__((ext_vector_type(4)));
typedef __bf16 v8bf __attribute__((ext_vector_type(8)));
typedef __bf16 v4bf __attribute__((ext_vector_type(4)));

#define BATCH  2
#define NQ     4096
#define MK     1024
#define DMODEL 512
#define DCTX   768
#define NH     8
#define DH     64

// W[K][512] fp32 -> Wt[512][K] bf16; block (0,0,0) also zero-inits scal[0..3]
// (kernel boundary orders this before any GEMM-epilogue atomicMax).
__global__ __launch_bounds__(256) void k_wtrans(
    const float* __restrict__ Wq, const float* __restrict__ Wk,
    const float* __restrict__ Wv, const float* __restrict__ Wo,
    __bf16* __restrict__ Wq_t, __bf16* __restrict__ Wk_t,
    __bf16* __restrict__ Wv_t, __bf16* __restrict__ Wo_t,
    unsigned* __restrict__ scal) {
  if (blockIdx.x == 0 && blockIdx.y == 0 && blockIdx.z == 0 && threadIdx.x < 4)
    scal[threadIdx.x] = 0u;
  const float* src; __bf16* dst; int K;
  switch (blockIdx.z) {
    case 0:  src = Wq; dst = Wq_t; K = DMODEL; break;
    case 1:  src = Wk; dst = Wk_t; K = DCTX;   break;
    case 2:  src = Wv; dst = Wv_t; K = DCTX;   break;
    default: src = Wo; dst = Wo_t; K = DMODEL; break;
  }
  int k0 = blockIdx.y * 32;
  if (k0 >= K) return;
  int n0 = blockIdx.x * 32;
  __shared__ __bf16 tile[32][33];
  int c = threadIdx.x & 31, r0 = threadIdx.x >> 5;
  for (int i = 0; i < 4; ++i) {
    int r = r0 + i * 8;
    tile[c][r] = (__bf16)src[(size_t)(k0 + r) * DMODEL + n0 + c];
  }
  __syncthreads();
  for (int i = 0; i < 4; ++i) {
    int r = r0 + i * 8;
    dst[(size_t)(n0 + r) * K + k0 + c] = tile[r][c];
  }
}

// C[M][N] = A[M][K](f32) @ Bt[N][K](bf16)^T, 64x64 tile, BK=64, 4 waves x 32x32.
// amax target: amaxLo for output cols < 512, amaxHi for cols >= 512.
template<bool BIAS, bool AMAX>
__global__ __launch_bounds__(256, 4) void k_gemm64(
    const float* __restrict__ A, const __bf16* __restrict__ Bt,
    float* __restrict__ C, int M, int N, int K,
    const float* __restrict__ bias,
    unsigned* __restrict__ amaxLo, unsigned* __restrict__ amaxHi) {
  __shared__ __bf16 As[64 * 76];  // stride 76 -> spread banks for b128 frag reads
  __shared__ __bf16 Bs[64 * 76];
  __shared__ float redmax[4];
  const int tid = threadIdx.x;
  const int lane = tid & 63, wave = tid >> 6;
  const int l15 = lane & 15, g = lane >> 4;
  const int row0 = blockIdx.x * 64, col0 = blockIdx.y * 64;
  const int wrow = (wave >> 1) * 32, wcol = (wave & 1) * 32;

  v4f acc[2][2] = {};

  for (int k0 = 0; k0 < K; k0 += 64) {
#pragma unroll
    for (int i = 0; i < 4; ++i) {   // A: 64x64 f32 -> bf16 (16 float4 per row)
      int f = tid + 256 * i;
      int r = f >> 4, c4 = (f & 15) << 2;
      float4 av = *(const float4*)(A + (size_t)(row0 + r) * K + k0 + c4);
      v4bf ap = { (__bf16)av.x, (__bf16)av.y, (__bf16)av.z, (__bf16)av.w };
      *(v4bf*)(&As[r * 76 + c4]) = ap;
    }
#pragma unroll
    for (int i = 0; i < 2; ++i) {   // B: 64x64 bf16 (8 v8bf per row)
      int f = tid + 256 * i;
      int r = f >> 3, c8 = (f & 7) << 3;
      *(v8bf*)(&Bs[r * 76 + c8]) =
          *(const v8bf*)(Bt + (size_t)(col0 + r) * K + k0 + c8);
    }
    __syncthreads();
#pragma unroll
    for (int c = 0; c < 2; ++c) {   // two K=32 chunks, accumulation order == BK32 version
      v8bf af0 = *(const v8bf*)(&As[(wrow + l15) * 76 + c * 32 + g * 8]);
      v8bf af1 = *(const v8bf*)(&As[(wrow + 16 + l15) * 76 + c * 32 + g * 8]);
      v8bf bf0 = *(const v8bf*)(&Bs[(wcol + l15) * 76 + c * 32 + g * 8]);
      v8bf bf1 = *(const v8bf*)(&Bs[(wcol + 16 + l15) * 76 + c * 32 + g * 8]);
      acc[0][0] = __builtin_amdgcn_mfma_f32_16x16x32_bf16(af0, bf0, acc[0][0], 0, 0, 0);
      acc[0][1] = __builtin_amdgcn_mfma_f32_16x16x32_bf16(af0, bf1, acc[0][1], 0, 0, 0);
      acc[1][0] = __builtin_amdgcn_mfma_f32_16x16x32_bf16(af1, bf0, acc[1][0], 0, 0, 0);
      acc[1][1] = __builtin_amdgcn_mfma_f32_16x16x32_bf16(af1, bf1, acc[1][1], 0, 0, 0);
    }
    __syncthreads();
  }

  float lmax = 0.0f;
#pragma unroll
  for (int j = 0; j < 2; ++j) {
    int col = col0 + wcol + j * 16 + l15;
    float bv = BIAS ? bias[col] : 0.0f;
#pragma unroll
    for (int i = 0; i < 2; ++i) {
#pragma unroll
      for (int r = 0; r < 4; ++r) {
        int row = row0 + wrow + i * 16 + g * 4 + r;  // C/D: col=lane&15, row=quad*4+reg
        float cv = acc[i][j][r] + bv;
        C[(size_t)row * N + col] = cv;
        if (AMAX) lmax = fmaxf(lmax, fabsf(cv));
      }
    }
  }
  if (AMAX) {
    for (int off = 32; off > 0; off >>= 1)
      lmax = fmaxf(lmax, __shfl_xor(lmax, off, 64));
    if (lane == 0) redmax[wave] = lmax;
    __syncthreads();
    if (tid == 0) {
      float bm = fmaxf(fmaxf(redmax[0], redmax[1]), fmaxf(redmax[2], redmax[3]));
      atomicMax(col0 < 512 ? amaxLo : amaxHi, __float_as_uint(bm));
    }
  }
}

// Merged quantization: blocks [0,4096) quantize q; [4096,5120) quantize k
// (from kvf cols 0..511, row stride 1024); [5120,5376) transpose-quantize v
// (kvf cols 512..1023 -> v8t[bh][dh][m]). Whole blocks per path -> no divergence.
__global__ __launch_bounds__(256) void k_quant_all(
    const float* __restrict__ qf, const float* __restrict__ kvf,
    int8_t* __restrict__ q8, int8_t* __restrict__ k8, int8_t* __restrict__ v8t,
    const unsigned* __restrict__ scal) {
  __shared__ int8_t tile[64][80];
  int bx = blockIdx.x;
  if (bx < 5120) {
    float4 v; int8_t* dst; float s;
    if (bx < 4096) {
      int idx = bx * 256 + threadIdx.x;
      v = ((const float4*)qf)[idx];
      dst = q8 + (size_t)idx * 4;
      s = 127.0f / __uint_as_float(scal[0]);
    } else {
      int j = (bx - 4096) * 256 + threadIdx.x;
      int r = j >> 7;             // 128 float4 per 512-wide k-row
      int c4 = (j & 127) << 2;
      v = *(const float4*)(kvf + (size_t)r * 1024 + c4);
      dst = k8 + (size_t)j * 4;   // j*4 == r*512 + c4
      s = 127.0f / __uint_as_float(scal[1]);
    }
    int a0 = __float2int_rn(v.x * s), a1 = __float2int_rn(v.y * s);
    int a2 = __float2int_rn(v.z * s), a3 = __float2int_rn(v.w * s);
    a0 = max(-128, min(127, a0)); a1 = max(-128, min(127, a1));
    a2 = max(-128, min(127, a2)); a3 = max(-128, min(127, a3));
    unsigned p = (unsigned)(a0 & 255) | ((unsigned)(a1 & 255) << 8) |
                 ((unsigned)(a2 & 255) << 16) | ((unsigned)(a3 & 255) << 24);
    *(unsigned*)dst = p;
    return;
  }
  // v transpose-quantize
  int id = bx - 5120;
  int bh = id >> 4, b = bh >> 3, h = bh & 7;
  int j0 = (id & 15) * 64;
  const float s = 127.0f / __uint_as_float(scal[2]);
  int t = threadIdx.x;
  int j = t >> 2, dh0 = (t & 3) << 4;
  const float* src = kvf + (size_t)(b * MK + j0 + j) * 1024 + 512 + h * DH + dh0;
#pragma unroll
  for (int i = 0; i < 16; i += 4) {
    float4 v = *(const float4*)(src + i);
    int a0 = __float2int_rn(v.x * s), a1 = __float2int_rn(v.y * s);
    int a2 = __float2int_rn(v.z * s), a3 = __float2int_rn(v.w * s);
    tile[dh0 + i + 0][j] = (int8_t)max(-128, min(127, a0));
    tile[dh0 + i + 1][j] = (int8_t)max(-128, min(127, a1));
    tile[dh0 + i + 2][j] = (int8_t)max(-128, min(127, a2));
    tile[dh0 + i + 3][j] = (int8_t)max(-128, min(127, a3));
  }
  __syncthreads();
  int dh = t >> 2, jb = (t & 3) << 4;
  v4i val = *(const v4i*)(&tile[dh][jb]);
  *(v4i*)(v8t + (size_t)(bh * DH + dh) * MK + j0 + jb) = val;
}

// pass 1: wave w owns keys [w*256,(w+1)*256); k-quarter register-resident.
// No-max z accumulation (scores tiny; exp2 can't overflow): z = sum exp2(s*a2).
__global__ __launch_bounds__(256, 4) void k_pass1(
    const int8_t* __restrict__ q8, const int8_t* __restrict__ k8,
    float* __restrict__ invz, unsigned* __restrict__ scal) {
  __shared__ float zbuf[4][64];
  __shared__ int   mbuf[4][64];
  int bh = blockIdx.y, b = bh >> 3, h = bh & 7;
  int wave = threadIdx.x >> 6, lane = threadIdx.x & 63;
  int l15 = lane & 15, g = lane >> 4;
  int row0 = blockIdx.x * 64;
  const float aq = __uint_as_float(scal[0]), ak = __uint_as_float(scal[1]);
  const float alpha2 = (aq * ak) * (0.125f / (127.0f * 127.0f)) * 1.44269504f;
  const v4i z4 = {0, 0, 0, 0};
  v4i qfrag[4];
#pragma unroll
  for (int rg = 0; rg < 4; ++rg)
    qfrag[rg] = *(const v4i*)(q8 + (size_t)(b * NQ + row0 + rg * 16 + l15) * DMODEL + h * DH + g * 16);
  const int8_t* kbase = k8 + (size_t)b * MK * DMODEL + h * DH + g * 16 +
                        (size_t)wave * 256 * DMODEL;
  v4i kf[16];
#pragma unroll
  for (int i = 0; i < 16; ++i)
    kf[i] = *(const v4i*)(kbase + (size_t)(i * 16 + l15) * DMODEL);

  float z[4] = {0.f, 0.f, 0.f, 0.f};
  int mi[4] = {-(1 << 30), -(1 << 30), -(1 << 30), -(1 << 30)};
#pragma unroll
  for (int kt = 0; kt < 16; ++kt) {
#pragma unroll
    for (int rg = 0; rg < 4; ++rg) {
      v4i sa = __builtin_amdgcn_mfma_i32_16x16x64_i8(kf[kt], qfrag[rg], z4, 0, 0, 0);
      mi[rg] = max(mi[rg], max(max(sa[0], sa[1]), max(sa[2], sa[3])));
      float e0 = __builtin_amdgcn_exp2f((float)sa[0] * alpha2);
      float e1 = __builtin_amdgcn_exp2f((float)sa[1] * alpha2);
      float e2 = __builtin_amdgcn_exp2f((float)sa[2] * alpha2);
      float e3 = __builtin_amdgcn_exp2f((float)sa[3] * alpha2);
      z[rg] += (e0 + e1) + (e2 + e3);
    }
  }
#pragma unroll
  for (int rg = 0; rg < 4; ++rg) {
    z[rg] += __shfl_xor(z[rg], 16, 64);
    mi[rg] = max(mi[rg], __shfl_xor(mi[rg], 16, 64));
    z[rg] += __shfl_xor(z[rg], 32, 64);
    mi[rg] = max(mi[rg], __shfl_xor(mi[rg], 32, 64));
  }
  if (lane < 16) {
#pragma unroll
    for (int rg = 0; rg < 4; ++rg) {
      zbuf[wave][rg * 16 + l15] = z[rg];
      mbuf[wave][rg * 16 + l15] = mi[rg];
    }
  }
  __syncthreads();
  if (threadIdx.x < 64) {
    int r = threadIdx.x;
    float zt = (zbuf[0][r] + zbuf[1][r]) + (zbuf[2][r] + zbuf[3][r]);
    int mt = max(max(mbuf[0][r], mbuf[1][r]), max(mbuf[2][r], mbuf[3][r]));
    float iz = 1.0f / zt;
    invz[(size_t)bh * NQ + row0 + r] = iz;
    float ma = __builtin_amdgcn_exp2f((float)mt * alpha2) * iz;  // row softmax max
    for (int off = 1; off < 64; off <<= 1)
      ma = fmaxf(ma, __shfl_xor(ma, off, 64));
    if (r == 0) atomicMax(scal + 3, __float_as_uint(ma));
  }
}

// pass 2 v5: wave w owns keys [w*256,(w+1)*256); k-quarter (16 v4i) and v-quarter
// (16 v4i) register-resident. Cross-wave reduction moved INSIDE the rg loop so
// only 4 pacc v4i are live at a time (v4 kept 16 live -> ~250 VGPRs at the 256
// cap, likely spilling). Summation tree unchanged -> bit-identical output.
__global__ __launch_bounds__(256, 2) void k_pass2(
    const int8_t* __restrict__ q8, const int8_t* __restrict__ k8,
    const int8_t* __restrict__ v8t, const float* __restrict__ invz,
    const unsigned* __restrict__ scal, float* __restrict__ o) {
  __shared__ __align__(16) int8_t attn_lds[4][16 * 80];  // 5 KB, wave-private
  __shared__ __align__(16) int redbuf[16][64][4];        // 16 KB cross-wave reduce
  int bh = blockIdx.y, b = bh >> 3, h = bh & 7;
  int wave = threadIdx.x >> 6, lane = threadIdx.x & 63;
  int l15 = lane & 15, g = lane >> 4;
  int row0 = blockIdx.x * 64;
  int key0 = wave * 256;
  const float aq = __uint_as_float(scal[0]), ak = __uint_as_float(scal[1]);
  const float avv = __uint_as_float(scal[2]), izm = __uint_as_float(scal[3]);
  const float alpha2 = (aq * ak) * (0.125f / (127.0f * 127.0f)) * 1.44269504f;
  const float oscale = (izm / 127.0f) * (avv / 127.0f);  // delta_attn * delta_v
  const float MAGIC = 12582912.0f;                       // 1.5 * 2^23
  const v4i z4 = {0, 0, 0, 0};

  v4i qfrag[4];
  float lc[4];
#pragma unroll
  for (int rg = 0; rg < 4; ++rg) {
    qfrag[rg] = *(const v4i*)(q8 + (size_t)(b * NQ + row0 + rg * 16 + l15) * DMODEL + h * DH + g * 16);
    // a = exp2(s*alpha2 + lc), lc = log2(invz * 127/izm), per q-row (row = rg*16+l15)
    lc[rg] = __builtin_amdgcn_logf(invz[(size_t)bh * NQ + row0 + rg * 16 + l15] * (127.0f / izm));
  }
  const int8_t* kbase = k8 + (size_t)(b * MK + key0) * DMODEL + h * DH + g * 16;
  v4i kf[16];
#pragma unroll
  for (int i = 0; i < 16; ++i)
    kf[i] = *(const v4i*)(kbase + (size_t)(i * 16 + l15) * DMODEL);
  const int8_t* vbase = v8t + (size_t)bh * DH * MK + key0 + g * 16;
  v4i vf[16];
#pragma unroll
  for (int d = 0; d < 4; ++d)
#pragma unroll
    for (int c = 0; c < 4; ++c)
      vf[d * 4 + c] = *(const v4i*)(vbase + (size_t)(d * 16 + l15) * MK + c * 64);

  int8_t* alds = attn_lds[wave];
  float* obase = o + (size_t)(b * NQ + row0) * DMODEL + h * DH;

#pragma unroll
  for (int rg = 0; rg < 4; ++rg) {
    const float lcr = lc[rg];
    v4i pacc[4] = {};
#pragma unroll
    for (int c = 0; c < 4; ++c) {
#pragma unroll
      for (int t = 0; t < 4; ++t) {
        v4i sa = __builtin_amdgcn_mfma_i32_16x16x64_i8(kf[c * 4 + t], qfrag[rg], z4, 0, 0, 0);
        float f0 = __builtin_amdgcn_exp2f(fmaf((float)sa[0], alpha2, lcr)) + MAGIC;
        float f1 = __builtin_amdgcn_exp2f(fmaf((float)sa[1], alpha2, lcr)) + MAGIC;
        float f2 = __builtin_amdgcn_exp2f(fmaf((float)sa[2], alpha2, lcr)) + MAGIC;
        float f3 = __builtin_amdgcn_exp2f(fmaf((float)sa[3], alpha2, lcr)) + MAGIC;
        unsigned packed = (__float_as_uint(f0) & 255u) |
                          ((__float_as_uint(f1) & 255u) << 8) |
                          ((__float_as_uint(f2) & 255u) << 16) |
                          (__float_as_uint(f3) << 24);
        // C-layout: col(l15)=q-row, row(g*4+r)=key -> store at [qrow][key_local]
        *(unsigned*)(alds + l15 * 80 + t * 16 + g * 4) = packed;
      }
      // wave-private LDS; DS pipe in-order per wave -> no barrier
      v4i afrag = *(const v4i*)(alds + l15 * 80 + g * 16);  // A-layout read
#pragma unroll
      for (int d = 0; d < 4; ++d)
        pacc[d] = __builtin_amdgcn_mfma_i32_16x16x64_i8(afrag, vf[d * 4 + c], pacc[d], 0, 0, 0);
    }
    // cross-wave reduction of this rg's key-partials + store (exact int32 sums)
    __syncthreads();  // also guards redbuf reuse from previous rg
#pragma unroll
    for (int d = 0; d < 4; ++d)
      *(v4i*)(&redbuf[wave * 4 + d][lane][0]) = pacc[d];
    __syncthreads();
    v4i s0 = *(const v4i*)(&redbuf[wave][lane][0]);
    v4i s1 = *(const v4i*)(&redbuf[4 + wave][lane][0]);
    v4i s2 = *(const v4i*)(&redbuf[8 + wave][lane][0]);
    v4i s3 = *(const v4i*)(&redbuf[12 + wave][lane][0]);
    v4i sum = (s0 + s1) + (s2 + s3);
#pragma unroll
    for (int r = 0; r < 4; ++r) {
      int row = rg * 16 + (lane >> 4) * 4 + r;
      obase[(size_t)row * DMODEL + wave * 16 + (lane & 15)] = (float)sum[r] * oscale;
    }
  }
}

extern "C" void kernel_launch(void* const* d_in, const int* in_sizes, int n_in,
                              void* d_out, int out_size, void* d_ws, size_t ws_size,
                              hipStream_t stream) {
  (void)in_sizes; (void)n_in; (void)out_size; (void)ws_size;
  const float* x   = (const float*)d_in[0];
  const float* ctx = (const float*)d_in[1];
  const float* Wq  = (const float*)d_in[2];
  const float* Wk  = (const float*)d_in[3];
  const float* Wv  = (const float*)d_in[4];
  const float* Wo  = (const float*)d_in[5];
  const float* bo  = (const float*)d_in[6];
  float* out = (float*)d_out;

  char* ws = (char*)d_ws;
  size_t off = 0;
  auto alloc = [&](size_t bytes) {
    char* p = ws + off;
    off += (bytes + 255) & ~(size_t)255;
    return p;
  };
  unsigned* scal = (unsigned*)alloc(16);
  __bf16* Wq_t = (__bf16*)alloc((size_t)512 * 512 * 2);
  __bf16* Wk_t = (__bf16*)alloc((size_t)512 * 768 * 2);  // contiguous with Wv_t:
  __bf16* Wv_t = (__bf16*)alloc((size_t)512 * 768 * 2);  //   B for fused kv GEMM (N=1024)
  __bf16* Wo_t = (__bf16*)alloc((size_t)512 * 512 * 2);
  float* qf  = (float*)alloc((size_t)BATCH * NQ * DMODEL * 4);   // later reused as o
  float* kvf = (float*)alloc((size_t)BATCH * MK * 1024 * 4);     // [2048][1024]: k | v
  int8_t* q8 = (int8_t*)alloc((size_t)BATCH * NQ * DMODEL);
  int8_t* k8 = (int8_t*)alloc((size_t)BATCH * MK * DMODEL);
  int8_t* v8t = (int8_t*)alloc((size_t)BATCH * NH * DH * MK);
  float* invz = (float*)alloc((size_t)BATCH * NH * NQ * 4);
  float* o = qf;  // q_f32 dead after quantization

  k_wtrans<<<dim3(16, 24, 4), 256, 0, stream>>>(Wq, Wk, Wv, Wo, Wq_t, Wk_t, Wv_t, Wo_t, scal);
  k_gemm64<false, true><<<dim3(128, 8), 256, 0, stream>>>(
      x, Wq_t, qf, 8192, 512, 512, nullptr, scal + 0, scal + 0);
  k_gemm64<false, true><<<dim3(32, 16), 256, 0, stream>>>(
      ctx, Wk_t, kvf, 2048, 1024, 768, nullptr, scal + 1, scal + 2);
  k_quant_all<<<5376, 256, 0, stream>>>(qf, kvf, q8, k8, v8t, scal);
  k_pass1<<<dim3(64, 16), 256, 0, stream>>>(q8, k8, invz, scal);
  k_pass2<<<dim3(64, 16), 256, 0, stream>>>(q8, k8, v8t, invz, scal, o);
  k_gemm64<true, false><<<dim3(128, 8), 256, 0, stream>>>(
      o, Wo_t, out, 8192, 512, 512, bo, nullptr, nullptr);
}